// Round 4
// baseline (779.692 us; speedup 1.0000x reference)
//
#include <hip/hip_runtime.h>
#include <hip/hip_bf16.h>

// MultiHeadAttention: B=4, S=1024, HIDDEN=2048, H=16, d=128, fp32 in/out.
// Pipeline (5 launches): fused cast->bf16, QKV gemm (+RoPE epilogue),
// V-transpose, flash attention (QK^T + softmax + PV fused; scores L2-only,
// writes mandatory fp32 attn_weights once + bf16 attn-out), output proj.
//
// ws layout (bf16 elems), peak 117,440,512 bytes, lifetimes verified disjoint:
//   Wob  [0,          4194304)   live: cast .. gemm_out
//   xb   [4194304,   12582912)   live: cast .. gemm_qkv
//   Wqkv [12582912,  25165824)   live: cast .. gemm_qkv
//   QKV  [25165824,  50331648)   live: gemm_qkv .. flash (V until transpose)
//   Vt   [50331648,  58720256)   live: transpose .. flash
//   AO   [4194304,   12582912)   overlays dead xb; live: flash .. gemm_out

typedef __attribute__((ext_vector_type(8))) short bf16x8;
typedef __attribute__((ext_vector_type(4))) float f32x4;

#define GLD_LDS16(g, l)                                                      \
  __builtin_amdgcn_global_load_lds(                                          \
      (const __attribute__((address_space(1))) unsigned int*)(g),            \
      (__attribute__((address_space(3))) unsigned int*)(l), 16, 0, 0)

// ---------------------------------------------------------------- fused cast fp32->bf16
__global__ __launch_bounds__(256) void cast_all(
    const float* __restrict__ x, const float* __restrict__ Wq,
    const float* __restrict__ Wk, const float* __restrict__ Wv,
    const float* __restrict__ Wo, __hip_bfloat16* __restrict__ ws) {
  int idx = blockIdx.x * 256 + threadIdx.x;
  const float* src;
  __hip_bfloat16* dst;
  int off;
  if (idx < 1048576) {
    src = x; dst = ws + 4194304; off = idx;             // xb
  } else if (idx < 1572864) {
    src = Wq; dst = ws + 12582912; off = idx - 1048576; // Wqb
  } else if (idx < 2097152) {
    src = Wk; dst = ws + 16777216; off = idx - 1572864; // Wkb
  } else if (idx < 2621440) {
    src = Wv; dst = ws + 20971520; off = idx - 2097152; // Wvb
  } else {
    src = Wo; dst = ws; off = idx - 2621440;            // Wob
  }
  const float4* p = (const float4*)src;
  float4 a = p[(size_t)off * 2], b = p[(size_t)off * 2 + 1];
  __hip_bfloat16 h[8] = {__float2bfloat16(a.x), __float2bfloat16(a.y),
                         __float2bfloat16(a.z), __float2bfloat16(a.w),
                         __float2bfloat16(b.x), __float2bfloat16(b.y),
                         __float2bfloat16(b.z), __float2bfloat16(b.w)};
  uint4 u;
  __builtin_memcpy(&u, h, 16);
  ((uint4*)dst)[off] = u;
}

// ---------------------------------------------------------------- QKV GEMM + fused RoPE
__global__ __launch_bounds__(256) void gemm_qkv(
    const __hip_bfloat16* __restrict__ A, const __hip_bfloat16* __restrict__ W,
    __hip_bfloat16* __restrict__ QKV) {
  __shared__ alignas(16) __hip_bfloat16 lA[128][64];
  __shared__ alignas(16) __hip_bfloat16 lB[128][64];

  const int tid = threadIdx.x;
  const int m0 = blockIdx.y * 128;
  const int n0 = blockIdx.x * 128;
  const int z = blockIdx.z;
  const __hip_bfloat16* Bm = W + (size_t)z * (2048 * 2048);

  const int lane = tid & 63;
  const int wid = tid >> 6;
  const int wm = wid * 32;
  const int frow = lane & 15;
  const int fk = (lane >> 4) * 8;

  f32x4 acc[2][8] = {};

  for (int k0 = 0; k0 < 2048; k0 += 64) {
    __syncthreads();
#pragma unroll
    for (int c = 0; c < 4; ++c) {
      int lin = c * 256 + tid;
      int r = lin >> 3;
      int col = (lin & 7) << 3;
      GLD_LDS16(A + (size_t)(m0 + r) * 2048 + k0 + col, &lA[r][col]);
    }
#pragma unroll
    for (int c = 0; c < 4; ++c) {
      int lin = c * 256 + tid;
      int r = lin >> 3;
      int col = (lin & 7) << 3;
      GLD_LDS16(Bm + (size_t)(n0 + r) * 2048 + k0 + col, &lB[r][col]);
    }
    __syncthreads();
#pragma unroll
    for (int kk = 0; kk < 64; kk += 32) {
      bf16x8 av[2], bv[8];
#pragma unroll
      for (int i = 0; i < 2; ++i)
        av[i] = *(const bf16x8*)&lA[wm + i * 16 + frow][kk + fk];
#pragma unroll
      for (int i = 0; i < 8; ++i)
        bv[i] = *(const bf16x8*)&lB[i * 16 + frow][kk + fk];
#pragma unroll
      for (int mi = 0; mi < 2; ++mi)
#pragma unroll
        for (int ni = 0; ni < 8; ++ni)
          acc[mi][ni] = __builtin_amdgcn_mfma_f32_16x16x32_bf16(
              av[mi], bv[ni], acc[mi][ni], 0, 0, 0);
    }
  }

  const int r0 = (lane >> 4) * 4;
  const int cc = lane & 15;
  __hip_bfloat16* C = QKV + (size_t)z * (4096 * 2048);

  if (z < 2) {
    float invf[4];
#pragma unroll
    for (int ni = 0; ni < 4; ++ni)
      invf[ni] = __expf(-(float)(ni * 16 + cc) * 0.143911568312128f);
#pragma unroll
    for (int mi = 0; mi < 2; ++mi) {
#pragma unroll
      for (int rr = 0; rr < 4; ++rr) {
        int m = m0 + wm + mi * 16 + r0 + rr;
        float spos = (float)(m & 1023);
        __hip_bfloat16* crow = C + (size_t)m * 2048 + n0;
#pragma unroll
        for (int ni = 0; ni < 4; ++ni) {
          float sn, c;
          __sincosf(spos * invf[ni], &sn, &c);  // sin FIRST, then cos
          float x1 = acc[mi][ni][rr], x2 = acc[mi][ni + 4][rr];
          crow[ni * 16 + cc] = __float2bfloat16(x1 * c - x2 * sn);
          crow[(ni + 4) * 16 + cc] = __float2bfloat16(x2 * c + x1 * sn);
        }
      }
    }
  } else {
#pragma unroll
    for (int mi = 0; mi < 2; ++mi)
#pragma unroll
      for (int ni = 0; ni < 8; ++ni)
#pragma unroll
        for (int rr = 0; rr < 4; ++rr)
          C[(size_t)(m0 + wm + mi * 16 + r0 + rr) * 2048 +
            (n0 + ni * 16 + cc)] = __float2bfloat16(acc[mi][ni][rr]);
  }
}

// ---------------------------------------------------------------- output projection
// out[m,n] = sum_k AO[m,k] * Wo[n,k]. M=4096 N=2048 K=2048, fp32 out.
__global__ __launch_bounds__(256) void gemm_out(
    const __hip_bfloat16* __restrict__ A, const __hip_bfloat16* __restrict__ Bm,
    float* __restrict__ Cbase) {
  __shared__ alignas(16) __hip_bfloat16 lA[128][64];
  __shared__ alignas(16) __hip_bfloat16 lB[128][64];

  const int tid = threadIdx.x;
  const int m0 = blockIdx.y * 128;
  const int n0 = blockIdx.x * 128;

  const int lane = tid & 63;
  const int wid = tid >> 6;
  const int wm = (wid & 1) * 64;
  const int wn = (wid >> 1) * 64;
  const int frow = lane & 15;
  const int fk = (lane >> 4) * 8;

  f32x4 acc[4][4] = {};

  for (int k0 = 0; k0 < 2048; k0 += 64) {
    __syncthreads();
#pragma unroll
    for (int c = 0; c < 4; ++c) {
      int lin = c * 256 + tid;
      int r = lin >> 3;
      int col = (lin & 7) << 3;
      GLD_LDS16(A + (size_t)(m0 + r) * 2048 + k0 + col, &lA[r][col]);
    }
#pragma unroll
    for (int c = 0; c < 4; ++c) {
      int lin = c * 256 + tid;
      int r = lin >> 3;
      int col = (lin & 7) << 3;
      GLD_LDS16(Bm + (size_t)(n0 + r) * 2048 + k0 + col, &lB[r][col]);
    }
    __syncthreads();
#pragma unroll
    for (int kk = 0; kk < 64; kk += 32) {
      bf16x8 av[4], bv[4];
#pragma unroll
      for (int i = 0; i < 4; ++i)
        av[i] = *(const bf16x8*)&lA[wm + i * 16 + frow][kk + fk];
#pragma unroll
      for (int i = 0; i < 4; ++i)
        bv[i] = *(const bf16x8*)&lB[wn + i * 16 + frow][kk + fk];
#pragma unroll
      for (int mi = 0; mi < 4; ++mi)
#pragma unroll
        for (int ni = 0; ni < 4; ++ni)
          acc[mi][ni] = __builtin_amdgcn_mfma_f32_16x16x32_bf16(
              av[mi], bv[ni], acc[mi][ni], 0, 0, 0);
    }
  }

  const int r0 = (lane >> 4) * 4;
  const int cc = lane & 15;
#pragma unroll
  for (int mi = 0; mi < 4; ++mi)
#pragma unroll
    for (int ni = 0; ni < 4; ++ni)
#pragma unroll
      for (int r = 0; r < 4; ++r)
        Cbase[(size_t)(m0 + wm + mi * 16 + r0 + r) * 2048 +
              (n0 + wn + ni * 16 + cc)] = acc[mi][ni][r];
}

// ---------------------------------------------------------------- V transpose [b,s,h,d] -> [b,h,d,s]
__global__ __launch_bounds__(256) void transpose_v(
    const __hip_bfloat16* __restrict__ Vb, __hip_bfloat16* __restrict__ Vt) {
  __shared__ short t[64][65];
  int s0 = blockIdx.x * 64;
  int j0 = blockIdx.y * 64;
  int bh = blockIdx.z;
  int b = bh >> 4, h = bh & 15;
  const short* src = (const short*)(Vb + ((size_t)b * 1024) * 2048 + h * 128);
#pragma unroll
  for (int it = 0; it < 2; ++it) {
    int lin = it * 256 + threadIdx.x;
    int r = lin >> 3, c8 = (lin & 7) * 8;
    bf16x8 v = *(const bf16x8*)&src[(size_t)(s0 + r) * 2048 + j0 + c8];
#pragma unroll
    for (int e = 0; e < 8; ++e) t[r][c8 + e] = v[e];
  }
  __syncthreads();
  short* dst = (short*)(Vt + ((size_t)bh * 128 + j0) * 1024 + s0);
#pragma unroll
  for (int it = 0; it < 2; ++it) {
    int lin = it * 256 + threadIdx.x;
    int r2 = lin >> 3, c8 = (lin & 7) * 8;
    bf16x8 w;
#pragma unroll
    for (int e = 0; e < 8; ++e) w[e] = t[c8 + e][r2];
    *(bf16x8*)&dst[(size_t)r2 * 1024 + c8] = w;
  }
}

// ---------------------------------------------------------------- fused flash attention
// One block per (strip, z). Strip rows [m0, m0+128), kv cols [0, m0+128).
// Pass 1: per kv-tile QK^T (Q in regs, K via global_load_lds), online per-row
//         (max,sum) in regs; row stats live in the 16 lanes owning the row in
//         the MFMA C-layout -> shfl_xor merge.
// Pass 2: QK^T again; write final fp32 attn_weights (mandatory output, only
//         HBM write); read back (L2-hot, first-touch-by-store so no stale L1)
//         via the staging map -> bf16 -> lP; PV MFMA vs Vt tile.
// Strips paired big+small via blockIdx.x mapping for CU load balance.
__global__ __launch_bounds__(256) void flash_attn(
    const __hip_bfloat16* __restrict__ Qb, const __hip_bfloat16* __restrict__ Kb,
    const __hip_bfloat16* __restrict__ Vt, const float* __restrict__ mask,
    float* __restrict__ Wout, __hip_bfloat16* __restrict__ AO) {
  __shared__ alignas(16) __hip_bfloat16 lK[64][128];
  __shared__ alignas(16) __hip_bfloat16 lV[128][64];
  __shared__ alignas(16) __hip_bfloat16 lP[128][64];

  const int tid = threadIdx.x;
  const int ssel = blockIdx.x;  // strip selector, pairs (16,2),(14,4),(12,6),(10,8) tiles
  const int z = blockIdx.y;     // b*16+h
  const int m0 = (ssel & 1) ? ((ssel >> 1) * 128) : ((7 - (ssel >> 1)) * 128);
  const int b = z >> 4, h = z & 15;
  const int NT = (m0 + 128) >> 6;

  const int lane = tid & 63;
  const int wid = tid >> 6;
  const int wm = wid * 32;
  const int frow = lane & 15;
  const int fk = (lane >> 4) * 8;
  const int r0 = (lane >> 4) * 4;
  const int cc = lane & 15;

  const __hip_bfloat16* Qh = Qb + ((size_t)b * 1024) * 2048 + h * 128;
  const __hip_bfloat16* Kh = Kb + ((size_t)b * 1024) * 2048 + h * 128;
  const __hip_bfloat16* Vh = Vt + (size_t)z * (128 * 1024);
  const float* mrow = mask + b * 1024;
  float* Sv = Wout + (size_t)z * (1024 * 1024);
  const float scale = 0.08838834764831845f;  // 1/sqrt(128)

  // Q fragments in registers: wave rows wm..wm+31, full d=128
  bf16x8 qf[2][4];
#pragma unroll
  for (int mi = 0; mi < 2; ++mi)
#pragma unroll
    for (int kq = 0; kq < 4; ++kq)
      qf[mi][kq] = *(const bf16x8*)
          &Qh[(size_t)(m0 + wm + mi * 16 + frow) * 2048 + kq * 32 + fk];

  float mx[2][4], sm[2][4];
#pragma unroll
  for (int mi = 0; mi < 2; ++mi)
#pragma unroll
    for (int rr = 0; rr < 4; ++rr) { mx[mi][rr] = -3.0e38f; sm[mi][rr] = 0.f; }

  // ---- pass 1: row stats
  for (int t = 0; t < NT; ++t) {
    const int j0 = t * 64;
    __syncthreads();
#pragma unroll
    for (int c = 0; c < 4; ++c) {
      int lin = c * 256 + tid;
      int r = lin >> 4;
      int col = (lin & 15) << 3;
      GLD_LDS16(Kh + (size_t)(j0 + r) * 2048 + col, &lK[r][col]);
    }
    __syncthreads();
    f32x4 as[2][4] = {};
#pragma unroll
    for (int kq = 0; kq < 4; ++kq) {
      bf16x8 bk[4];
#pragma unroll
      for (int ni = 0; ni < 4; ++ni)
        bk[ni] = *(const bf16x8*)&lK[ni * 16 + frow][kq * 32 + fk];
#pragma unroll
      for (int mi = 0; mi < 2; ++mi)
#pragma unroll
        for (int ni = 0; ni < 4; ++ni)
          as[mi][ni] = __builtin_amdgcn_mfma_f32_16x16x32_bf16(
              qf[mi][kq], bk[ni], as[mi][ni], 0, 0, 0);
    }
    float mk[4];
#pragma unroll
    for (int ni = 0; ni < 4; ++ni) mk[ni] = mrow[j0 + ni * 16 + cc];
#pragma unroll
    for (int mi = 0; mi < 2; ++mi) {
#pragma unroll
      for (int rr = 0; rr < 4; ++rr) {
        const int i = m0 + wm + mi * 16 + r0 + rr;
        float sv[4];
        bool ok[4];
#pragma unroll
        for (int ni = 0; ni < 4; ++ni) {
          int j = j0 + ni * 16 + cc;
          ok[ni] = (j <= i);
          sv[ni] = ok[ni] ? as[mi][ni][rr] * scale + mk[ni] : -3.0e38f;
        }
        float tm = fmaxf(fmaxf(sv[0], sv[1]), fmaxf(sv[2], sv[3]));
        if (tm > mx[mi][rr]) {
          sm[mi][rr] *= __expf(mx[mi][rr] - tm);
          mx[mi][rr] = tm;
        }
#pragma unroll
        for (int ni = 0; ni < 4; ++ni)
          sm[mi][rr] += ok[ni] ? __expf(sv[ni] - mx[mi][rr]) : 0.f;
      }
    }
  }

  // merge across the 16 lanes (cc) sharing each row
  float inv[2][4];
#pragma unroll
  for (int mi = 0; mi < 2; ++mi) {
#pragma unroll
    for (int rr = 0; rr < 4; ++rr) {
#pragma unroll
      for (int off = 1; off < 16; off <<= 1) {
        float om = __shfl_xor(mx[mi][rr], off, 64);
        float os = __shfl_xor(sm[mi][rr], off, 64);
        float nm = fmaxf(mx[mi][rr], om);
        sm[mi][rr] = sm[mi][rr] * __expf(mx[mi][rr] - nm) + os * __expf(om - nm);
        mx[mi][rr] = nm;
      }
      inv[mi][rr] = 1.0f / sm[mi][rr];
    }
  }

  // ---- pass 2: weights + PV
  f32x4 acc[2][8] = {};
  for (int t = 0; t < NT; ++t) {
    const int j0 = t * 64;
    __syncthreads();  // protect lK/lV/lP reuse from previous iter's reads
#pragma unroll
    for (int c = 0; c < 4; ++c) {
      int lin = c * 256 + tid;
      int r = lin >> 4;
      int col = (lin & 15) << 3;
      GLD_LDS16(Kh + (size_t)(j0 + r) * 2048 + col, &lK[r][col]);
    }
#pragma unroll
    for (int c = 0; c < 4; ++c) {
      int lin = c * 256 + tid;
      int r = lin >> 3;
      int col = (lin & 7) << 3;
      GLD_LDS16(Vh + (size_t)r * 1024 + j0 + col, &lV[r][col]);
    }
    __syncthreads();
    f32x4 as[2][4] = {};
#pragma unroll
    for (int kq = 0; kq < 4; ++kq) {
      bf16x8 bk[4];
#pragma unroll
      for (int ni = 0; ni < 4; ++ni)
        bk[ni] = *(const bf16x8*)&lK[ni * 16 + frow][kq * 32 + fk];
#pragma unroll
      for (int mi = 0; mi < 2; ++mi)
#pragma unroll
        for (int ni = 0; ni < 4; ++ni)
          as[mi][ni] = __builtin_amdgcn_mfma_f32_16x16x32_bf16(
              qf[mi][kq], bk[ni], as[mi][ni], 0, 0, 0);
    }
    float mk[4];
#pragma unroll
    for (int ni = 0; ni < 4; ++ni) mk[ni] = mrow[j0 + ni * 16 + cc];
    // final weights store (mandatory fp32 output)
#pragma unroll
    for (int mi = 0; mi < 2; ++mi) {
#pragma unroll
      for (int rr = 0; rr < 4; ++rr) {
        const int i = m0 + wm + mi * 16 + r0 + rr;
#pragma unroll
        for (int ni = 0; ni < 4; ++ni) {
          int j = j0 + ni * 16 + cc;
          float w = (j <= i)
                        ? __expf(as[mi][ni][rr] * scale + mk[ni] - mx[mi][rr]) *
                              inv[mi][rr]
                        : 0.f;
          Sv[(size_t)i * 1024 + j] = w;
        }
      }
    }
    __syncthreads();  // drain stores (vmcnt0 at barrier) -> visible block-wide
    // read back (L2-hot) via staging map -> bf16 -> lP
#pragma unroll
    for (int c = 0; c < 8; ++c) {
      int lin = c * 256 + tid;
      int r = lin >> 4;
      int col = (lin & 15) << 2;
      float4 v = *(const float4*)&Sv[(size_t)(m0 + r) * 1024 + j0 + col];
      __hip_bfloat16 hh[4] = {__float2bfloat16(v.x), __float2bfloat16(v.y),
                              __float2bfloat16(v.z), __float2bfloat16(v.w)};
      unsigned long long u;
      __builtin_memcpy(&u, hh, 8);
      *(unsigned long long*)&lP[r][col] = u;
    }
    __syncthreads();  // lP written by all waves, read across waves
    // PV
#pragma unroll
    for (int kj = 0; kj < 64; kj += 32) {
      bf16x8 av[2], bv[8];
#pragma unroll
      for (int mi = 0; mi < 2; ++mi)
        av[mi] = *(const bf16x8*)&lP[wm + mi * 16 + frow][kj + fk];
#pragma unroll
      for (int ni = 0; ni < 8; ++ni)
        bv[ni] = *(const bf16x8*)&lV[ni * 16 + frow][kj + fk];
#pragma unroll
      for (int mi = 0; mi < 2; ++mi)
#pragma unroll
        for (int ni = 0; ni < 8; ++ni)
          acc[mi][ni] = __builtin_amdgcn_mfma_f32_16x16x32_bf16(
              av[mi], bv[ni], acc[mi][ni], 0, 0, 0);
    }
  }

  // epilogue: attn_out[b, i, h*128 + d], bf16
  __hip_bfloat16* C = AO + ((size_t)b * 1024) * 2048 + h * 128;
#pragma unroll
  for (int mi = 0; mi < 2; ++mi)
#pragma unroll
    for (int ni = 0; ni < 8; ++ni)
#pragma unroll
      for (int rr = 0; rr < 4; ++rr)
        C[(size_t)(m0 + wm + mi * 16 + r0 + rr) * 2048 + ni * 16 + cc] =
            __float2bfloat16(acc[mi][ni][rr]);
}

// ---------------------------------------------------------------- launch
extern "C" void kernel_launch(void* const* d_in, const int* in_sizes, int n_in,
                              void* d_out, int out_size, void* d_ws,
                              size_t ws_size, hipStream_t stream) {
  const float* x = (const float*)d_in[0];
  const float* mask = (const float*)d_in[1];
  const float* Wq = (const float*)d_in[2];
  const float* Wk = (const float*)d_in[3];
  const float* Wv = (const float*)d_in[4];
  const float* Wo = (const float*)d_in[5];
  float* out = (float*)d_out;
  float* attnw = out + (size_t)4 * 1024 * 2048;  // fp32 weights region of d_out

  __hip_bfloat16* wsb = (__hip_bfloat16*)d_ws;
  __hip_bfloat16* Wob = wsb;                 //  4,194,304
  __hip_bfloat16* xb  = wsb + 4194304;       //  8,388,608
  __hip_bfloat16* Wqb = wsb + 12582912;      //  3x 4,194,304 (Wq,Wk,Wv contig)
  __hip_bfloat16* Qb  = wsb + 25165824;      //  3x 8,388,608 (Q,K,V contig)
  __hip_bfloat16* Kb  = wsb + 33554432;
  __hip_bfloat16* Vb  = wsb + 41943040;
  __hip_bfloat16* Vt  = wsb + 50331648;      //  8,388,608
  __hip_bfloat16* AO  = wsb + 4194304;       //  8,388,608 (overlays dead xb)

  cast_all<<<12288, 256, 0, stream>>>(x, Wq, Wk, Wv, Wo, wsb);
  gemm_qkv<<<dim3(16, 32, 3), 256, 0, stream>>>(xb, Wqb, Qb);
  transpose_v<<<dim3(16, 2, 64), 256, 0, stream>>>(Vb, Vt);
  flash_attn<<<dim3(8, 64), 256, 0, stream>>>(Qb, Kb, Vt, mask, attnw, AO);
  gemm_out<<<dim3(16, 32), 256, 0, stream>>>(AO, Wob, out);
}

// Round 6
// 768.615 us; speedup vs baseline: 1.0144x; 1.0144x over previous
//
#include <hip/hip_runtime.h>
#include <hip/hip_bf16.h>

// MultiHeadAttention: B=4, S=1024, HIDDEN=2048, H=16, d=128, fp32 in/out.
// Pipeline (5 launches): fused cast->bf16, QKV gemm (+RoPE epilogue, V written
// directly transposed), QK^T scores (+softmax row-stat partials per
// column-half in epilogue), fused softmax-finish + PV gemm (single pass;
// writes fp32 attn_weights + bf16 attn-out), output projection.
//
// ws layout (bf16 elems), peak 117,440,512 bytes, lifetimes verified disjoint:
//   Wob  [0,          4194304)   live: cast .. gemm_out
//   xb   [4194304,   12582912)   live: cast .. gemm_qkv
//   Wqkv [12582912,  25165824)   live: cast .. gemm_qkv
//   part [12582912,  16777216)   overlays dead Wqkv; live: scores .. pv (8MB)
//   QKV  [25165824,  50331648)   live: gemm_qkv .. pv (z=2 slot unused now)
//   Vt   [50331648,  58720256)   live: gemm_qkv .. pv
//   AO   [4194304,   12582912)   overlays dead xb; live: pv .. gemm_out

typedef __attribute__((ext_vector_type(8))) short bf16x8;
typedef __attribute__((ext_vector_type(4))) float f32x4;

#define GLD_LDS16(g, l)                                                      \
  __builtin_amdgcn_global_load_lds(                                          \
      (const __attribute__((address_space(1))) unsigned int*)(g),            \
      (__attribute__((address_space(3))) unsigned int*)(l), 16, 0, 0)

// ---------------------------------------------------------------- fused cast fp32->bf16
__global__ __launch_bounds__(256) void cast_all(
    const float* __restrict__ x, const float* __restrict__ Wq,
    const float* __restrict__ Wk, const float* __restrict__ Wv,
    const float* __restrict__ Wo, __hip_bfloat16* __restrict__ ws) {
  int idx = blockIdx.x * 256 + threadIdx.x;
  const float* src;
  __hip_bfloat16* dst;
  int off;
  if (idx < 1048576) {
    src = x; dst = ws + 4194304; off = idx;             // xb
  } else if (idx < 1572864) {
    src = Wq; dst = ws + 12582912; off = idx - 1048576; // Wqb
  } else if (idx < 2097152) {
    src = Wk; dst = ws + 16777216; off = idx - 1572864; // Wkb
  } else if (idx < 2621440) {
    src = Wv; dst = ws + 20971520; off = idx - 2097152; // Wvb
  } else {
    src = Wo; dst = ws; off = idx - 2621440;            // Wob
  }
  const float4* p = (const float4*)src;
  float4 a = p[(size_t)off * 2], b = p[(size_t)off * 2 + 1];
  __hip_bfloat16 h[8] = {__float2bfloat16(a.x), __float2bfloat16(a.y),
                         __float2bfloat16(a.z), __float2bfloat16(a.w),
                         __float2bfloat16(b.x), __float2bfloat16(b.y),
                         __float2bfloat16(b.z), __float2bfloat16(b.w)};
  uint4 u;
  __builtin_memcpy(&u, h, 16);
  ((uint4*)dst)[off] = u;
}

// ---------------------------------------------------------------- QKV GEMM + fused RoPE + V-transpose
// C[m,n] = sum_k x[m,k] * W[n,k], z in {0,1,2} selects Wq/Wk/Wv.
// Wave mapping: wm = wid*32; wn spans the full 128-wide n-tile so the RoPE
// pair (j, j+64) = (ni, ni+4) lives in ONE lane. z<2: RoPE on fp32 acc.
// z==2: V written directly transposed into Vt[((b*16+h)*128+d)*1024 + s]
// (rr walks consecutive s -> 8B contiguous stores; kills transpose_v kernel).
__global__ __launch_bounds__(256) void gemm_qkv(
    const __hip_bfloat16* __restrict__ A, const __hip_bfloat16* __restrict__ W,
    __hip_bfloat16* __restrict__ QKV, __hip_bfloat16* __restrict__ Vt) {
  __shared__ alignas(16) __hip_bfloat16 lA[128][64];
  __shared__ alignas(16) __hip_bfloat16 lB[128][64];

  const int tid = threadIdx.x;
  const int m0 = blockIdx.y * 128;
  const int n0 = blockIdx.x * 128;
  const int z = blockIdx.z;
  const __hip_bfloat16* Bm = W + (size_t)z * (2048 * 2048);

  const int lane = tid & 63;
  const int wid = tid >> 6;
  const int wm = wid * 32;
  const int frow = lane & 15;
  const int fk = (lane >> 4) * 8;

  f32x4 acc[2][8] = {};

  for (int k0 = 0; k0 < 2048; k0 += 64) {
    __syncthreads();
#pragma unroll
    for (int c = 0; c < 4; ++c) {
      int lin = c * 256 + tid;
      int r = lin >> 3;
      int col = (lin & 7) << 3;
      GLD_LDS16(A + (size_t)(m0 + r) * 2048 + k0 + col, &lA[r][col]);
    }
#pragma unroll
    for (int c = 0; c < 4; ++c) {
      int lin = c * 256 + tid;
      int r = lin >> 3;
      int col = (lin & 7) << 3;
      GLD_LDS16(Bm + (size_t)(n0 + r) * 2048 + k0 + col, &lB[r][col]);
    }
    __syncthreads();
#pragma unroll
    for (int kk = 0; kk < 64; kk += 32) {
      bf16x8 av[2], bv[8];
#pragma unroll
      for (int i = 0; i < 2; ++i)
        av[i] = *(const bf16x8*)&lA[wm + i * 16 + frow][kk + fk];
#pragma unroll
      for (int i = 0; i < 8; ++i)
        bv[i] = *(const bf16x8*)&lB[i * 16 + frow][kk + fk];
#pragma unroll
      for (int mi = 0; mi < 2; ++mi)
#pragma unroll
        for (int ni = 0; ni < 8; ++ni)
          acc[mi][ni] = __builtin_amdgcn_mfma_f32_16x16x32_bf16(
              av[mi], bv[ni], acc[mi][ni], 0, 0, 0);
    }
  }

  const int r0 = (lane >> 4) * 4;
  const int cc = lane & 15;
  __hip_bfloat16* C = QKV + (size_t)z * (4096 * 2048);

  if (z < 2) {
    float invf[4];
#pragma unroll
    for (int ni = 0; ni < 4; ++ni)
      invf[ni] = __expf(-(float)(ni * 16 + cc) * 0.143911568312128f);
#pragma unroll
    for (int mi = 0; mi < 2; ++mi) {
#pragma unroll
      for (int rr = 0; rr < 4; ++rr) {
        int m = m0 + wm + mi * 16 + r0 + rr;
        float spos = (float)(m & 1023);
        __hip_bfloat16* crow = C + (size_t)m * 2048 + n0;
#pragma unroll
        for (int ni = 0; ni < 4; ++ni) {
          float sn, c;
          __sincosf(spos * invf[ni], &sn, &c);  // sin FIRST, then cos
          float x1 = acc[mi][ni][rr], x2 = acc[mi][ni + 4][rr];
          crow[ni * 16 + cc] = __float2bfloat16(x1 * c - x2 * sn);
          crow[(ni + 4) * 16 + cc] = __float2bfloat16(x2 * c + x1 * sn);
        }
      }
    }
  } else {
    // V: direct transposed write. n-tile spans exactly one head (d=128).
    const int hh = n0 >> 7;
#pragma unroll
    for (int mi = 0; mi < 2; ++mi) {
      int m = m0 + wm + mi * 16 + r0;  // +rr walks consecutive s
      int bb = m >> 10;
      int s = m & 1023;
      __hip_bfloat16* vdst = Vt + (((size_t)bb * 16 + hh) * 128) * 1024;
#pragma unroll
      for (int ni = 0; ni < 8; ++ni) {
        int d = ni * 16 + cc;
        __hip_bfloat16 hv[4] = {__float2bfloat16(acc[mi][ni][0]),
                                __float2bfloat16(acc[mi][ni][1]),
                                __float2bfloat16(acc[mi][ni][2]),
                                __float2bfloat16(acc[mi][ni][3])};
        unsigned long long u;
        __builtin_memcpy(&u, hv, 8);
        *(unsigned long long*)&vdst[(size_t)d * 1024 + s] = u;
      }
    }
  }
}

// ---------------------------------------------------------------- scores GEMM + row-stat partials
// S[i,j] = (q_i . k_j)/sqrt(128), z=b*16+h, tiles with n0>m0 skipped.
// Epilogue ALSO computes per-tile per-COLUMN-HALF per-row (max, sum-exp)
// partials (16-lane shfl_xor butterfly). Slot = ((z,y)*8 + x)*2 + (wn>>6):
// unique writer wave per slot (waves 0/1: half 0 rows 0-63/64-127; 2/3: half 1).
__global__ __launch_bounds__(256) void gemm_scores(
    const __hip_bfloat16* __restrict__ Qb, const __hip_bfloat16* __restrict__ Kb,
    const float* __restrict__ mask, float* __restrict__ Cbase,
    float* __restrict__ part) {
  __shared__ alignas(16) __hip_bfloat16 lA[128][64];
  __shared__ alignas(16) __hip_bfloat16 lB[128][64];

  const int tid = threadIdx.x;
  const int m0 = blockIdx.y * 128;
  const int n0 = blockIdx.x * 128;
  if (n0 > m0) return;  // tile fully above causal diagonal
  const int z = blockIdx.z;
  const int b = z >> 4, h = z & 15;
  const __hip_bfloat16* A = Qb + ((size_t)b * 1024) * 2048 + h * 128;
  const __hip_bfloat16* Bm = Kb + ((size_t)b * 1024) * 2048 + h * 128;

  const int lane = tid & 63;
  const int wid = tid >> 6;
  const int wm = (wid & 1) * 64;
  const int wn = (wid >> 1) * 64;
  const int frow = lane & 15;
  const int fk = (lane >> 4) * 8;

  f32x4 acc[4][4] = {};

  for (int k0 = 0; k0 < 128; k0 += 64) {
    __syncthreads();
#pragma unroll
    for (int c = 0; c < 4; ++c) {
      int lin = c * 256 + tid;
      int r = lin >> 3;
      int col = (lin & 7) << 3;
      GLD_LDS16(A + (size_t)(m0 + r) * 2048 + k0 + col, &lA[r][col]);
    }
#pragma unroll
    for (int c = 0; c < 4; ++c) {
      int lin = c * 256 + tid;
      int r = lin >> 3;
      int col = (lin & 7) << 3;
      GLD_LDS16(Bm + (size_t)(n0 + r) * 2048 + k0 + col, &lB[r][col]);
    }
    __syncthreads();
#pragma unroll
    for (int kk = 0; kk < 64; kk += 32) {
      bf16x8 av[4], bv[4];
#pragma unroll
      for (int i = 0; i < 4; ++i)
        av[i] = *(const bf16x8*)&lA[wm + i * 16 + frow][kk + fk];
#pragma unroll
      for (int i = 0; i < 4; ++i)
        bv[i] = *(const bf16x8*)&lB[wn + i * 16 + frow][kk + fk];
#pragma unroll
      for (int mi = 0; mi < 4; ++mi)
#pragma unroll
        for (int ni = 0; ni < 4; ++ni)
          acc[mi][ni] = __builtin_amdgcn_mfma_f32_16x16x32_bf16(
              av[mi], bv[ni], acc[mi][ni], 0, 0, 0);
    }
  }

  const int r0 = (lane >> 4) * 4;
  const int cc = lane & 15;
  const float scale = 0.08838834764831845f;  // 1/sqrt(128)
  float* C = Cbase + (size_t)z * (1024 * 1024);

  // raw (scaled) score write
#pragma unroll
  for (int mi = 0; mi < 4; ++mi)
#pragma unroll
    for (int ni = 0; ni < 4; ++ni)
#pragma unroll
      for (int r = 0; r < 4; ++r)
        C[(size_t)(m0 + wm + mi * 16 + r0 + r) * 1024 +
          (n0 + wn + ni * 16 + cc)] = acc[mi][ni][r] * scale;

  // per-row (max, sum-exp) partials for this tile's column half
  const float* mrow = mask + b * 1024;
  float mk2[4];
#pragma unroll
  for (int ni = 0; ni < 4; ++ni) mk2[ni] = mrow[n0 + wn + ni * 16 + cc];
  float2* p2 = (float2*)part +
               (((((size_t)z * 8 + blockIdx.y) * 8 + blockIdx.x) * 2 +
                 (wid >> 1))) * 128;
#pragma unroll
  for (int mi = 0; mi < 4; ++mi) {
#pragma unroll
    for (int r = 0; r < 4; ++r) {
      const int i = m0 + wm + mi * 16 + r0 + r;
      float sv[4];
      bool ok[4];
#pragma unroll
      for (int ni = 0; ni < 4; ++ni) {
        int j = n0 + wn + ni * 16 + cc;
        ok[ni] = (j <= i);
        sv[ni] = ok[ni] ? acc[mi][ni][r] * scale + mk2[ni] : -3.0e38f;
      }
      float lm = fmaxf(fmaxf(sv[0], sv[1]), fmaxf(sv[2], sv[3]));
      float ls = 0.f;
#pragma unroll
      for (int ni = 0; ni < 4; ++ni)
        ls += ok[ni] ? __expf(sv[ni] - lm) : 0.f;
#pragma unroll
      for (int off = 1; off < 16; off <<= 1) {
        float om = __shfl_xor(lm, off, 64);
        float os = __shfl_xor(ls, off, 64);
        float nm = fmaxf(lm, om);
        ls = ls * __expf(lm - nm) + os * __expf(om - nm);
        lm = nm;
      }
      if (cc == 0) p2[wm + mi * 16 + r0 + r] = float2{lm, ls};
    }
  }
}

// ---------------------------------------------------------------- softmax-finish + PV GEMM (single pass)
// One block per (z, m-strip). Prologue: merge the 2*(ytile+1) half-tile
// partials per row -> (mx, 1/sum) in LDS, hoisted to registers. Single pass:
// w = exp(s - mx)*inv, write fp32 attn_weights in place (strip only;
// beyond-strip zeros come from harness memset), bf16 -> lA, MFMA vs Vt.
__global__ __launch_bounds__(256) void gemm_pv(
    float* __restrict__ Sb, const __hip_bfloat16* __restrict__ Vt,
    const float* __restrict__ mask, const float* __restrict__ part,
    __hip_bfloat16* __restrict__ AO) {
  __shared__ alignas(16) __hip_bfloat16 lA[128][64];
  __shared__ alignas(16) __hip_bfloat16 lB[128][64];
  __shared__ float smx[128], sinv[128];

  const int tid = threadIdx.x;
  const int z = blockIdx.x;              // b*16+h
  const int ytile = 7 - blockIdx.y;      // big strips dispatch first
  const int m0 = ytile * 128;
  const int b = z >> 4, h = z & 15;
  float* S = Sb + (size_t)z * (1024 * 1024);
  const __hip_bfloat16* Bm = Vt + (size_t)z * (128 * 1024);
  const float* mrow = mask + b * 1024;
  const int K = m0 + 128;

  // ---- merge per-half-tile partials -> row stats
  if (tid < 128) {
    const float2* pp =
        (const float2*)part + ((size_t)z * 8 + ytile) * 16 * 128;
    float m = -3.0e38f, s = 0.f;
    for (int x = 0; x < 2 * (ytile + 1); ++x) {
      float2 p = pp[x * 128 + tid];
      float nm = fmaxf(m, p.x);
      s = s * __expf(m - nm) + p.y * __expf(p.x - nm);
      m = nm;
    }
    smx[tid] = m;
    sinv[tid] = 1.0f / s;
  }
  __syncthreads();

  // staging map: each row handled by 16 consecutive lanes
  const int sr = tid >> 4;
  const int scol = (tid & 15) << 2;
  float mx[8], inv[8];
#pragma unroll
  for (int c = 0; c < 8; ++c) {
    mx[c] = smx[c * 16 + sr];
    inv[c] = sinv[c * 16 + sr];
  }

  const int lane = tid & 63;
  const int wid = tid >> 6;
  const int wm = (wid & 1) * 64;
  const int wn = (wid >> 1) * 64;
  const int frow = lane & 15;
  const int fk = (lane >> 4) * 8;

  f32x4 acc[4][4] = {};

  for (int k0 = 0; k0 < K; k0 += 64) {
    __syncthreads();
    float4 mk = *(const float4*)&mrow[k0 + scol];
#pragma unroll
    for (int c = 0; c < 8; ++c) {
      int r = c * 16 + sr;
      int i = m0 + r;
      size_t soff = (size_t)i * 1024 + k0 + scol;
      float4 v = *(const float4*)&S[soff];
      float s[4] = {v.x + mk.x, v.y + mk.y, v.z + mk.z, v.w + mk.w};
      int j = k0 + scol;
      float w[4];
#pragma unroll
      for (int e = 0; e < 4; ++e)
        w[e] = (j + e <= i && s[e] > -1.0e38f) ? __expf(s[e] - mx[c]) * inv[c]
                                               : 0.f;
      float4 o = {w[0], w[1], w[2], w[3]};
      *(float4*)&S[soff] = o;  // fp32 attn_weights output (in place)
      __hip_bfloat16 hh[4] = {__float2bfloat16(w[0]), __float2bfloat16(w[1]),
                              __float2bfloat16(w[2]), __float2bfloat16(w[3])};
      unsigned long long u;
      __builtin_memcpy(&u, hh, 8);
      *(unsigned long long*)&lA[r][scol] = u;
    }
#pragma unroll
    for (int c = 0; c < 4; ++c) {
      int lin = c * 256 + tid;
      int r = lin >> 3;
      int col = (lin & 7) << 3;
      GLD_LDS16(Bm + (size_t)r * 1024 + k0 + col, &lB[r][col]);
    }
    __syncthreads();
#pragma unroll
    for (int kk = 0; kk < 64; kk += 32) {
      bf16x8 av[4], bv[4];
#pragma unroll
      for (int i = 0; i < 4; ++i)
        av[i] = *(const bf16x8*)&lA[wm + i * 16 + frow][kk + fk];
#pragma unroll
      for (int i = 0; i < 4; ++i)
        bv[i] = *(const bf16x8*)&lB[wn + i * 16 + frow][kk + fk];
#pragma unroll
      for (int mi = 0; mi < 4; ++mi)
#pragma unroll
        for (int ni = 0; ni < 4; ++ni)
          acc[mi][ni] = __builtin_amdgcn_mfma_f32_16x16x32_bf16(
              av[mi], bv[ni], acc[mi][ni], 0, 0, 0);
    }
  }

  // epilogue: attn_out[b, i, h*128 + d], bf16
  const int r0 = (lane >> 4) * 4;
  const int cc = lane & 15;
  __hip_bfloat16* C = AO + ((size_t)b * 1024) * 2048 + h * 128;
#pragma unroll
  for (int mi = 0; mi < 4; ++mi)
#pragma unroll
    for (int ni = 0; ni < 4; ++ni)
#pragma unroll
      for (int r = 0; r < 4; ++r)
        C[(size_t)(m0 + wm + mi * 16 + r0 + r) * 2048 +
          (wn + ni * 16 + cc)] = __float2bfloat16(acc[mi][ni][r]);
}

// ---------------------------------------------------------------- output projection
// out[m,n] = sum_k AO[m,k] * Wo[n,k]. M=4096 N=2048 K=2048, fp32 out.
__global__ __launch_bounds__(256) void gemm_out(
    const __hip_bfloat16* __restrict__ A, const __hip_bfloat16* __restrict__ Bm,
    float* __restrict__ Cbase) {
  __shared__ alignas(16) __hip_bfloat16 lA[128][64];
  __shared__ alignas(16) __hip_bfloat16 lB[128][64];

  const int tid = threadIdx.x;
  const int m0 = blockIdx.y * 128;
  const int n0 = blockIdx.x * 128;

  const int lane = tid & 63;
  const int wid = tid >> 6;
  const int wm = (wid & 1) * 64;
  const int wn = (wid >> 1) * 64;
  const int frow = lane & 15;
  const int fk = (lane >> 4) * 8;

  f32x4 acc[4][4] = {};

  for (int k0 = 0; k0 < 2048; k0 += 64) {
    __syncthreads();
#pragma unroll
    for (int c = 0; c < 4; ++c) {
      int lin = c * 256 + tid;
      int r = lin >> 3;
      int col = (lin & 7) << 3;
      GLD_LDS16(A + (size_t)(m0 + r) * 2048 + k0 + col, &lA[r][col]);
    }
#pragma unroll
    for (int c = 0; c < 4; ++c) {
      int lin = c * 256 + tid;
      int r = lin >> 3;
      int col = (lin & 7) << 3;
      GLD_LDS16(Bm + (size_t)(n0 + r) * 2048 + k0 + col, &lB[r][col]);
    }
    __syncthreads();
#pragma unroll
    for (int kk = 0; kk < 64; kk += 32) {
      bf16x8 av[4], bv[4];
#pragma unroll
      for (int i = 0; i < 4; ++i)
        av[i] = *(const bf16x8*)&lA[wm + i * 16 + frow][kk + fk];
#pragma unroll
      for (int i = 0; i < 4; ++i)
        bv[i] = *(const bf16x8*)&lB[wn + i * 16 + frow][kk + fk];
#pragma unroll
      for (int mi = 0; mi < 4; ++mi)
#pragma unroll
        for (int ni = 0; ni < 4; ++ni)
          acc[mi][ni] = __builtin_amdgcn_mfma_f32_16x16x32_bf16(
              av[mi], bv[ni], acc[mi][ni], 0, 0, 0);
    }
  }

  const int r0 = (lane >> 4) * 4;
  const int cc = lane & 15;
#pragma unroll
  for (int mi = 0; mi < 4; ++mi)
#pragma unroll
    for (int ni = 0; ni < 4; ++ni)
#pragma unroll
      for (int r = 0; r < 4; ++r)
        Cbase[(size_t)(m0 + wm + mi * 16 + r0 + r) * 2048 +
              (n0 + wn + ni * 16 + cc)] = acc[mi][ni][r];
}

// ---------------------------------------------------------------- launch
extern "C" void kernel_launch(void* const* d_in, const int* in_sizes, int n_in,
                              void* d_out, int out_size, void* d_ws,
                              size_t ws_size, hipStream_t stream) {
  const float* x = (const float*)d_in[0];
  const float* mask = (const float*)d_in[1];
  const float* Wq = (const float*)d_in[2];
  const float* Wk = (const float*)d_in[3];
  const float* Wv = (const float*)d_in[4];
  const float* Wo = (const float*)d_in[5];
  float* out = (float*)d_out;
  float* attnw = out + (size_t)4 * 1024 * 2048;  // fp32 weights region of d_out

  __hip_bfloat16* wsb = (__hip_bfloat16*)d_ws;
  __hip_bfloat16* Wob = wsb;                 //  4,194,304
  __hip_bfloat16* xb  = wsb + 4194304;       //  8,388,608
  __hip_bfloat16* Wqb = wsb + 12582912;      //  3x 4,194,304 (Wq,Wk,Wv contig)
  __hip_bfloat16* Qb  = wsb + 25165824;      //  3x 8,388,608 (Q,K slots used)
  __hip_bfloat16* Kb  = wsb + 33554432;
  __hip_bfloat16* Vt  = wsb + 50331648;      //  8,388,608
  __hip_bfloat16* AO  = wsb + 4194304;       //  8,388,608 (overlays dead xb)
  float* part = (float*)(wsb + 12582912);    //  8MB (overlays dead Wqkv)

  cast_all<<<12288, 256, 0, stream>>>(x, Wq, Wk, Wv, Wo, wsb);
  gemm_qkv<<<dim3(16, 32, 3), 256, 0, stream>>>(xb, Wqb, Qb, Vt);
  gemm_scores<<<dim3(8, 8, 64), 256, 0, stream>>>(Qb, Kb, mask, attnw, part);
  gemm_pv<<<dim3(64, 8), 256, 0, stream>>>(attnw, Vt, mask, part, AO);
  gemm_out<<<dim3(16, 32), 256, 0, stream>>>(AO, Wob, out);
}

// Round 7
// 729.500 us; speedup vs baseline: 1.0688x; 1.0536x over previous
//
#include <hip/hip_runtime.h>
#include <hip/hip_bf16.h>

// MultiHeadAttention: B=4, S=1024, HIDDEN=2048, H=16, d=128, fp32 in/out.
// Pipeline (5 launches): fused cast->bf16, QKV gemm (+RoPE epilogue, V written
// directly transposed), QK^T scores (writes EXP'D half-tile-max-normalized
// values + per-half row partials), fused softmax-finish + PV gemm (scale-only
// pass; writes fp32 attn_weights + bf16 attn-out), output projection.
//
// ws layout (bf16 elems), peak 117,440,512 bytes, lifetimes verified disjoint:
//   Wob  [0,          4194304)   live: cast .. gemm_out
//   xb   [4194304,   12582912)   live: cast .. gemm_qkv
//   Wqkv [12582912,  25165824)   live: cast .. gemm_qkv
//   part [12582912,  16777216)   overlays dead Wqkv; live: scores .. pv (8MB)
//   QKV  [25165824,  50331648)   live: gemm_qkv .. pv (z=2 slot unused now)
//   Vt   [50331648,  58720256)   live: gemm_qkv .. pv
//   AO   [4194304,   12582912)   overlays dead xb; live: pv .. gemm_out

typedef __attribute__((ext_vector_type(8))) short bf16x8;
typedef __attribute__((ext_vector_type(4))) float f32x4;

#define GLD_LDS16(g, l)                                                      \
  __builtin_amdgcn_global_load_lds(                                          \
      (const __attribute__((address_space(1))) unsigned int*)(g),            \
      (__attribute__((address_space(3))) unsigned int*)(l), 16, 0, 0)

// ---------------------------------------------------------------- fused cast fp32->bf16
__global__ __launch_bounds__(256) void cast_all(
    const float* __restrict__ x, const float* __restrict__ Wq,
    const float* __restrict__ Wk, const float* __restrict__ Wv,
    const float* __restrict__ Wo, __hip_bfloat16* __restrict__ ws) {
  int idx = blockIdx.x * 256 + threadIdx.x;
  const float* src;
  __hip_bfloat16* dst;
  int off;
  if (idx < 1048576) {
    src = x; dst = ws + 4194304; off = idx;             // xb
  } else if (idx < 1572864) {
    src = Wq; dst = ws + 12582912; off = idx - 1048576; // Wqb
  } else if (idx < 2097152) {
    src = Wk; dst = ws + 16777216; off = idx - 1572864; // Wkb
  } else if (idx < 2621440) {
    src = Wv; dst = ws + 20971520; off = idx - 2097152; // Wvb
  } else {
    src = Wo; dst = ws; off = idx - 2621440;            // Wob
  }
  const float4* p = (const float4*)src;
  float4 a = p[(size_t)off * 2], b = p[(size_t)off * 2 + 1];
  __hip_bfloat16 h[8] = {__float2bfloat16(a.x), __float2bfloat16(a.y),
                         __float2bfloat16(a.z), __float2bfloat16(a.w),
                         __float2bfloat16(b.x), __float2bfloat16(b.y),
                         __float2bfloat16(b.z), __float2bfloat16(b.w)};
  uint4 u;
  __builtin_memcpy(&u, h, 16);
  ((uint4*)dst)[off] = u;
}

// ---------------------------------------------------------------- QKV GEMM + fused RoPE + V-transpose
// C[m,n] = sum_k x[m,k] * W[n,k], z in {0,1,2} selects Wq/Wk/Wv.
// Wave mapping: wm = wid*32; wn spans the full 128-wide n-tile so the RoPE
// pair (j, j+64) = (ni, ni+4) lives in ONE lane. z<2: RoPE on fp32 acc.
// z==2: V written directly transposed into Vt[((b*16+h)*128+d)*1024 + s].
__global__ __launch_bounds__(256) void gemm_qkv(
    const __hip_bfloat16* __restrict__ A, const __hip_bfloat16* __restrict__ W,
    __hip_bfloat16* __restrict__ QKV, __hip_bfloat16* __restrict__ Vt) {
  __shared__ alignas(16) __hip_bfloat16 lA[128][64];
  __shared__ alignas(16) __hip_bfloat16 lB[128][64];

  const int tid = threadIdx.x;
  const int m0 = blockIdx.y * 128;
  const int n0 = blockIdx.x * 128;
  const int z = blockIdx.z;
  const __hip_bfloat16* Bm = W + (size_t)z * (2048 * 2048);

  const int lane = tid & 63;
  const int wid = tid >> 6;
  const int wm = wid * 32;
  const int frow = lane & 15;
  const int fk = (lane >> 4) * 8;

  f32x4 acc[2][8] = {};

  for (int k0 = 0; k0 < 2048; k0 += 64) {
    __syncthreads();
#pragma unroll
    for (int c = 0; c < 4; ++c) {
      int lin = c * 256 + tid;
      int r = lin >> 3;
      int col = (lin & 7) << 3;
      GLD_LDS16(A + (size_t)(m0 + r) * 2048 + k0 + col, &lA[r][col]);
    }
#pragma unroll
    for (int c = 0; c < 4; ++c) {
      int lin = c * 256 + tid;
      int r = lin >> 3;
      int col = (lin & 7) << 3;
      GLD_LDS16(Bm + (size_t)(n0 + r) * 2048 + k0 + col, &lB[r][col]);
    }
    __syncthreads();
#pragma unroll
    for (int kk = 0; kk < 64; kk += 32) {
      bf16x8 av[2], bv[8];
#pragma unroll
      for (int i = 0; i < 2; ++i)
        av[i] = *(const bf16x8*)&lA[wm + i * 16 + frow][kk + fk];
#pragma unroll
      for (int i = 0; i < 8; ++i)
        bv[i] = *(const bf16x8*)&lB[i * 16 + frow][kk + fk];
#pragma unroll
      for (int mi = 0; mi < 2; ++mi)
#pragma unroll
        for (int ni = 0; ni < 8; ++ni)
          acc[mi][ni] = __builtin_amdgcn_mfma_f32_16x16x32_bf16(
              av[mi], bv[ni], acc[mi][ni], 0, 0, 0);
    }
  }

  const int r0 = (lane >> 4) * 4;
  const int cc = lane & 15;
  __hip_bfloat16* C = QKV + (size_t)z * (4096 * 2048);

  if (z < 2) {
    float invf[4];
#pragma unroll
    for (int ni = 0; ni < 4; ++ni)
      invf[ni] = __expf(-(float)(ni * 16 + cc) * 0.143911568312128f);
#pragma unroll
    for (int mi = 0; mi < 2; ++mi) {
#pragma unroll
      for (int rr = 0; rr < 4; ++rr) {
        int m = m0 + wm + mi * 16 + r0 + rr;
        float spos = (float)(m & 1023);
        __hip_bfloat16* crow = C + (size_t)m * 2048 + n0;
#pragma unroll
        for (int ni = 0; ni < 4; ++ni) {
          float sn, c;
          __sincosf(spos * invf[ni], &sn, &c);  // sin FIRST, then cos
          float x1 = acc[mi][ni][rr], x2 = acc[mi][ni + 4][rr];
          crow[ni * 16 + cc] = __float2bfloat16(x1 * c - x2 * sn);
          crow[(ni + 4) * 16 + cc] = __float2bfloat16(x2 * c + x1 * sn);
        }
      }
    }
  } else {
    // V: direct transposed write. n-tile spans exactly one head (d=128).
    const int hh = n0 >> 7;
#pragma unroll
    for (int mi = 0; mi < 2; ++mi) {
      int m = m0 + wm + mi * 16 + r0;  // +rr walks consecutive s
      int bb = m >> 10;
      int s = m & 1023;
      __hip_bfloat16* vdst = Vt + (((size_t)bb * 16 + hh) * 128) * 1024;
#pragma unroll
      for (int ni = 0; ni < 8; ++ni) {
        int d = ni * 16 + cc;
        __hip_bfloat16 hv[4] = {__float2bfloat16(acc[mi][ni][0]),
                                __float2bfloat16(acc[mi][ni][1]),
                                __float2bfloat16(acc[mi][ni][2]),
                                __float2bfloat16(acc[mi][ni][3])};
        unsigned long long u;
        __builtin_memcpy(&u, hv, 8);
        *(unsigned long long*)&vdst[(size_t)d * 1024 + s] = u;
      }
    }
  }
}

// ---------------------------------------------------------------- scores GEMM, exp'd output + partials
// z=b*16+h, tiles with n0>m0 skipped. For each row i and 64-col half:
//   lm = max_j(s_ij + mask_j) over the half (shfl butterfly over 16 lanes)
//   write exp(s+mk-lm) (0 above diagonal) to attnw; partial (lm, sum-exp).
// Slot = ((z*8+y)*8+x)*2 + half: unique writer wave per slot.
__global__ __launch_bounds__(256) void gemm_scores(
    const __hip_bfloat16* __restrict__ Qb, const __hip_bfloat16* __restrict__ Kb,
    const float* __restrict__ mask, float* __restrict__ Cbase,
    float* __restrict__ part) {
  __shared__ alignas(16) __hip_bfloat16 lA[128][64];
  __shared__ alignas(16) __hip_bfloat16 lB[128][64];

  const int tid = threadIdx.x;
  const int m0 = blockIdx.y * 128;
  const int n0 = blockIdx.x * 128;
  if (n0 > m0) return;  // tile fully above causal diagonal
  const int z = blockIdx.z;
  const int b = z >> 4, h = z & 15;
  const __hip_bfloat16* A = Qb + ((size_t)b * 1024) * 2048 + h * 128;
  const __hip_bfloat16* Bm = Kb + ((size_t)b * 1024) * 2048 + h * 128;

  const int lane = tid & 63;
  const int wid = tid >> 6;
  const int wm = (wid & 1) * 64;
  const int wn = (wid >> 1) * 64;
  const int frow = lane & 15;
  const int fk = (lane >> 4) * 8;

  f32x4 acc[4][4] = {};

  for (int k0 = 0; k0 < 128; k0 += 64) {
    __syncthreads();
#pragma unroll
    for (int c = 0; c < 4; ++c) {
      int lin = c * 256 + tid;
      int r = lin >> 3;
      int col = (lin & 7) << 3;
      GLD_LDS16(A + (size_t)(m0 + r) * 2048 + k0 + col, &lA[r][col]);
    }
#pragma unroll
    for (int c = 0; c < 4; ++c) {
      int lin = c * 256 + tid;
      int r = lin >> 3;
      int col = (lin & 7) << 3;
      GLD_LDS16(Bm + (size_t)(n0 + r) * 2048 + k0 + col, &lB[r][col]);
    }
    __syncthreads();
#pragma unroll
    for (int kk = 0; kk < 64; kk += 32) {
      bf16x8 av[4], bv[4];
#pragma unroll
      for (int i = 0; i < 4; ++i)
        av[i] = *(const bf16x8*)&lA[wm + i * 16 + frow][kk + fk];
#pragma unroll
      for (int i = 0; i < 4; ++i)
        bv[i] = *(const bf16x8*)&lB[wn + i * 16 + frow][kk + fk];
#pragma unroll
      for (int mi = 0; mi < 4; ++mi)
#pragma unroll
        for (int ni = 0; ni < 4; ++ni)
          acc[mi][ni] = __builtin_amdgcn_mfma_f32_16x16x32_bf16(
              av[mi], bv[ni], acc[mi][ni], 0, 0, 0);
    }
  }

  const int r0 = (lane >> 4) * 4;
  const int cc = lane & 15;
  const float scale = 0.08838834764831845f;  // 1/sqrt(128)
  float* C = Cbase + (size_t)z * (1024 * 1024);
  const float* mrow = mask + b * 1024;
  float mk2[4];
#pragma unroll
  for (int ni = 0; ni < 4; ++ni) mk2[ni] = mrow[n0 + wn + ni * 16 + cc];
  float2* p2 = (float2*)part +
               (((((size_t)z * 8 + blockIdx.y) * 8 + blockIdx.x) * 2 +
                 (wid >> 1))) * 128;

#pragma unroll
  for (int mi = 0; mi < 4; ++mi) {
#pragma unroll
    for (int r = 0; r < 4; ++r) {
      const int i = m0 + wm + mi * 16 + r0 + r;
      float sv[4];
      bool ok[4];
#pragma unroll
      for (int ni = 0; ni < 4; ++ni) {
        int j = n0 + wn + ni * 16 + cc;
        ok[ni] = (j <= i);
        sv[ni] = ok[ni] ? acc[mi][ni][r] * scale + mk2[ni] : -3.0e38f;
      }
      // half-tile row max first (diag tiles always have >=1 valid col/row)
      float lm = fmaxf(fmaxf(sv[0], sv[1]), fmaxf(sv[2], sv[3]));
#pragma unroll
      for (int off = 1; off < 16; off <<= 1)
        lm = fmaxf(lm, __shfl_xor(lm, off, 64));
      float ev[4];
      float ls = 0.f;
#pragma unroll
      for (int ni = 0; ni < 4; ++ni) {
        ev[ni] = ok[ni] ? __expf(sv[ni] - lm) : 0.f;
        ls += ev[ni];
      }
#pragma unroll
      for (int off = 1; off < 16; off <<= 1) ls += __shfl_xor(ls, off, 64);
      float* crow = &C[(size_t)i * 1024 + n0 + wn + cc];
#pragma unroll
      for (int ni = 0; ni < 4; ++ni) crow[ni * 16] = ev[ni];
      if (cc == 0) p2[wm + mi * 16 + r0 + r] = float2{lm, ls};
    }
  }
}

// ---------------------------------------------------------------- softmax-finish + PV GEMM (scale-only)
// One block per (z, m-strip). Prologue: merge 2*(ytile+1) half-tile partials
// per row -> global (mx, inv); fac[x][row] = exp(lm_x - mx)*inv in LDS.
// Main loop: w = S * fac (no exp/mask on critical path), write fp32
// attn_weights in place, bf16 -> lA, MFMA vs Vt.
__global__ __launch_bounds__(256) void gemm_pv(
    float* __restrict__ Sb, const __hip_bfloat16* __restrict__ Vt,
    const float* __restrict__ part, __hip_bfloat16* __restrict__ AO) {
  __shared__ alignas(16) __hip_bfloat16 lA[128][64];
  __shared__ alignas(16) __hip_bfloat16 lB[128][64];
  __shared__ float lfac[16][128];

  const int tid = threadIdx.x;
  const int z = blockIdx.x;              // b*16+h
  const int ytile = 7 - blockIdx.y;      // big strips dispatch first
  const int m0 = ytile * 128;
  const int b = z >> 4, h = z & 15;
  float* S = Sb + (size_t)z * (1024 * 1024);
  const __hip_bfloat16* Bm = Vt + (size_t)z * (128 * 1024);
  const int K = m0 + 128;
  const int nx = 2 * (ytile + 1);

  // ---- merge per-half-tile partials -> per-half factors
  if (tid < 128) {
    const float2* pp =
        (const float2*)part + ((size_t)z * 8 + ytile) * 16 * 128;
    float m = -3.0e38f, s = 0.f;
    for (int x = 0; x < nx; ++x) {
      float2 p = pp[x * 128 + tid];
      float nm = fmaxf(m, p.x);
      s = s * __expf(m - nm) + p.y * __expf(p.x - nm);
      m = nm;
    }
    float iv = 1.0f / s;
    for (int x = 0; x < nx; ++x)
      lfac[x][tid] = __expf(pp[x * 128 + tid].x - m) * iv;
  }
  __syncthreads();

  // staging map: each row handled by 16 consecutive lanes
  const int sr = tid >> 4;
  const int scol = (tid & 15) << 2;

  const int lane = tid & 63;
  const int wid = tid >> 6;
  const int wm = (wid & 1) * 64;
  const int wn = (wid >> 1) * 64;
  const int frow = lane & 15;
  const int fk = (lane >> 4) * 8;

  f32x4 acc[4][4] = {};

  for (int k0 = 0; k0 < K; k0 += 64) {
    __syncthreads();
    const int xk = k0 >> 6;
#pragma unroll
    for (int c = 0; c < 8; ++c) {
      int r = c * 16 + sr;
      size_t soff = (size_t)(m0 + r) * 1024 + k0 + scol;
      float4 v = *(const float4*)&S[soff];
      float fc = lfac[xk][r];
      float4 o = {v.x * fc, v.y * fc, v.z * fc, v.w * fc};
      *(float4*)&S[soff] = o;  // fp32 attn_weights output (in place)
      __hip_bfloat16 hh[4] = {__float2bfloat16(o.x), __float2bfloat16(o.y),
                              __float2bfloat16(o.z), __float2bfloat16(o.w)};
      unsigned long long u;
      __builtin_memcpy(&u, hh, 8);
      *(unsigned long long*)&lA[r][scol] = u;
    }
#pragma unroll
    for (int c = 0; c < 4; ++c) {
      int lin = c * 256 + tid;
      int r = lin >> 3;
      int col = (lin & 7) << 3;
      GLD_LDS16(Bm + (size_t)r * 1024 + k0 + col, &lB[r][col]);
    }
    __syncthreads();
#pragma unroll
    for (int kk = 0; kk < 64; kk += 32) {
      bf16x8 av[4], bv[4];
#pragma unroll
      for (int i = 0; i < 4; ++i)
        av[i] = *(const bf16x8*)&lA[wm + i * 16 + frow][kk + fk];
#pragma unroll
      for (int i = 0; i < 4; ++i)
        bv[i] = *(const bf16x8*)&lB[wn + i * 16 + frow][kk + fk];
#pragma unroll
      for (int mi = 0; mi < 4; ++mi)
#pragma unroll
        for (int ni = 0; ni < 4; ++ni)
          acc[mi][ni] = __builtin_amdgcn_mfma_f32_16x16x32_bf16(
              av[mi], bv[ni], acc[mi][ni], 0, 0, 0);
    }
  }

  // epilogue: attn_out[b, i, h*128 + d], bf16
  const int r0 = (lane >> 4) * 4;
  const int cc = lane & 15;
  __hip_bfloat16* C = AO + ((size_t)b * 1024) * 2048 + h * 128;
#pragma unroll
  for (int mi = 0; mi < 4; ++mi)
#pragma unroll
    for (int ni = 0; ni < 4; ++ni)
#pragma unroll
      for (int r = 0; r < 4; ++r)
        C[(size_t)(m0 + wm + mi * 16 + r0 + r) * 2048 +
          (wn + ni * 16 + cc)] = __float2bfloat16(acc[mi][ni][r]);
}

// ---------------------------------------------------------------- output projection
// out[m,n] = sum_k AO[m,k] * Wo[n,k]. M=4096 N=2048 K=2048, fp32 out.
__global__ __launch_bounds__(256) void gemm_out(
    const __hip_bfloat16* __restrict__ A, const __hip_bfloat16* __restrict__ Bm,
    float* __restrict__ Cbase) {
  __shared__ alignas(16) __hip_bfloat16 lA[128][64];
  __shared__ alignas(16) __hip_bfloat16 lB[128][64];

  const int tid = threadIdx.x;
  const int m0 = blockIdx.y * 128;
  const int n0 = blockIdx.x * 128;

  const int lane = tid & 63;
  const int wid = tid >> 6;
  const int wm = (wid & 1) * 64;
  const int wn = (wid >> 1) * 64;
  const int frow = lane & 15;
  const int fk = (lane >> 4) * 8;

  f32x4 acc[4][4] = {};

  for (int k0 = 0; k0 < 2048; k0 += 64) {
    __syncthreads();
#pragma unroll
    for (int c = 0; c < 4; ++c) {
      int lin = c * 256 + tid;
      int r = lin >> 3;
      int col = (lin & 7) << 3;
      GLD_LDS16(A + (size_t)(m0 + r) * 2048 + k0 + col, &lA[r][col]);
    }
#pragma unroll
    for (int c = 0; c < 4; ++c) {
      int lin = c * 256 + tid;
      int r = lin >> 3;
      int col = (lin & 7) << 3;
      GLD_LDS16(Bm + (size_t)(n0 + r) * 2048 + k0 + col, &lB[r][col]);
    }
    __syncthreads();
#pragma unroll
    for (int kk = 0; kk < 64; kk += 32) {
      bf16x8 av[4], bv[4];
#pragma unroll
      for (int i = 0; i < 4; ++i)
        av[i] = *(const bf16x8*)&lA[wm + i * 16 + frow][kk + fk];
#pragma unroll
      for (int i = 0; i < 4; ++i)
        bv[i] = *(const bf16x8*)&lB[wn + i * 16 + frow][kk + fk];
#pragma unroll
      for (int mi = 0; mi < 4; ++mi)
#pragma unroll
        for (int ni = 0; ni < 4; ++ni)
          acc[mi][ni] = __builtin_amdgcn_mfma_f32_16x16x32_bf16(
              av[mi], bv[ni], acc[mi][ni], 0, 0, 0);
    }
  }

  const int r0 = (lane >> 4) * 4;
  const int cc = lane & 15;
#pragma unroll
  for (int mi = 0; mi < 4; ++mi)
#pragma unroll
    for (int ni = 0; ni < 4; ++ni)
#pragma unroll
      for (int r = 0; r < 4; ++r)
        Cbase[(size_t)(m0 + wm + mi * 16 + r0 + r) * 2048 +
              (n0 + wn + ni * 16 + cc)] = acc[mi][ni][r];
}

// ---------------------------------------------------------------- launch
extern "C" void kernel_launch(void* const* d_in, const int* in_sizes, int n_in,
                              void* d_out, int out_size, void* d_ws,
                              size_t ws_size, hipStream_t stream) {
  const float* x = (const float*)d_in[0];
  const float* mask = (const float*)d_in[1];
  const float* Wq = (const float*)d_in[2];
  const float* Wk = (const float*)d_in[3];
  const float* Wv = (const float*)d_in[4];
  const float* Wo = (const float*)d_in[5];
  float* out = (float*)d_out;
  float* attnw = out + (size_t)4 * 1024 * 2048;  // fp32 weights region of d_out

  __hip_bfloat16* wsb = (__hip_bfloat16*)d_ws;
  __hip_bfloat16* Wob = wsb;                 //  4,194,304
  __hip_bfloat16* xb  = wsb + 4194304;       //  8,388,608
  __hip_bfloat16* Wqb = wsb + 12582912;      //  3x 4,194,304 (Wq,Wk,Wv contig)
  __hip_bfloat16* Qb  = wsb + 25165824;      //  3x 8,388,608 (Q,K slots used)
  __hip_bfloat16* Kb  = wsb + 33554432;
  __hip_bfloat16* Vt  = wsb + 50331648;      //  8,388,608
  __hip_bfloat16* AO  = wsb + 4194304;       //  8,388,608 (overlays dead xb)
  float* part = (float*)(wsb + 12582912);    //  8MB (overlays dead Wqkv)

  cast_all<<<12288, 256, 0, stream>>>(x, Wq, Wk, Wv, Wo, wsb);
  gemm_qkv<<<dim3(16, 32, 3), 256, 0, stream>>>(xb, Wqb, Qb, Vt);
  gemm_scores<<<dim3(8, 8, 64), 256, 0, stream>>>(Qb, Kb, mask, attnw, part);
  gemm_pv<<<dim3(64, 8), 256, 0, stream>>>(attnw, Vt, part, AO);
  gemm_out<<<dim3(16, 32), 256, 0, stream>>>(AO, Wob, out);
}

// Round 8
// 682.494 us; speedup vs baseline: 1.1424x; 1.0689x over previous
//
#include <hip/hip_runtime.h>
#include <hip/hip_bf16.h>

// MultiHeadAttention: B=4, S=1024, HIDDEN=2048, H=16, d=128, fp32 in/out.
// Pipeline (6 launches): fused cast->bf16, QKV gemm (+RoPE epilogue, V written
// directly transposed), qk_stats (k-chunked row max/sumexp partials),
// QK^T scores (merge stats, write FINAL fp32 attn_weights once),
// PV gemm (plain: weights->bf16->LDS, MFMA vs Vt -> attn-out), output proj.
//
// ws layout (bf16 elems), peak 117,440,512 bytes, lifetimes verified disjoint:
//   Wob   [0,          4194304)   live: cast .. gemm_out
//   xb    [4194304,   12582912)   live: cast .. gemm_qkv
//   Wqkv  [12582912,  25165824)   live: cast .. gemm_qkv
//   pstat [12582912,  13631488)   overlays dead Wqkv; live: stats .. scores (2MB)
//   QKV   [25165824,  50331648)   live: gemm_qkv .. pv (V slot unused)
//   Vt    [50331648,  58720256)   live: gemm_qkv .. pv
//   AO    [4194304,   12582912)   overlays dead xb; live: pv .. gemm_out

typedef __attribute__((ext_vector_type(8))) short bf16x8;
typedef __attribute__((ext_vector_type(4))) float f32x4;

#define GLD_LDS16(g, l)                                                      \
  __builtin_amdgcn_global_load_lds(                                          \
      (const __attribute__((address_space(1))) unsigned int*)(g),            \
      (__attribute__((address_space(3))) unsigned int*)(l), 16, 0, 0)

// ---------------------------------------------------------------- fused cast fp32->bf16
__global__ __launch_bounds__(256) void cast_all(
    const float* __restrict__ x, const float* __restrict__ Wq,
    const float* __restrict__ Wk, const float* __restrict__ Wv,
    const float* __restrict__ Wo, __hip_bfloat16* __restrict__ ws) {
  int idx = blockIdx.x * 256 + threadIdx.x;
  const float* src;
  __hip_bfloat16* dst;
  int off;
  if (idx < 1048576) {
    src = x; dst = ws + 4194304; off = idx;             // xb
  } else if (idx < 1572864) {
    src = Wq; dst = ws + 12582912; off = idx - 1048576; // Wqb
  } else if (idx < 2097152) {
    src = Wk; dst = ws + 16777216; off = idx - 1572864; // Wkb
  } else if (idx < 2621440) {
    src = Wv; dst = ws + 20971520; off = idx - 2097152; // Wvb
  } else {
    src = Wo; dst = ws; off = idx - 2621440;            // Wob
  }
  const float4* p = (const float4*)src;
  float4 a = p[(size_t)off * 2], b = p[(size_t)off * 2 + 1];
  __hip_bfloat16 h[8] = {__float2bfloat16(a.x), __float2bfloat16(a.y),
                         __float2bfloat16(a.z), __float2bfloat16(a.w),
                         __float2bfloat16(b.x), __float2bfloat16(b.y),
                         __float2bfloat16(b.z), __float2bfloat16(b.w)};
  uint4 u;
  __builtin_memcpy(&u, h, 16);
  ((uint4*)dst)[off] = u;
}

// ---------------------------------------------------------------- QKV GEMM + fused RoPE + V-transpose
__global__ __launch_bounds__(256) void gemm_qkv(
    const __hip_bfloat16* __restrict__ A, const __hip_bfloat16* __restrict__ W,
    __hip_bfloat16* __restrict__ QKV, __hip_bfloat16* __restrict__ Vt) {
  __shared__ alignas(16) __hip_bfloat16 lA[128][64];
  __shared__ alignas(16) __hip_bfloat16 lB[128][64];

  const int tid = threadIdx.x;
  const int m0 = blockIdx.y * 128;
  const int n0 = blockIdx.x * 128;
  const int z = blockIdx.z;
  const __hip_bfloat16* Bm = W + (size_t)z * (2048 * 2048);

  const int lane = tid & 63;
  const int wid = tid >> 6;
  const int wm = wid * 32;
  const int frow = lane & 15;
  const int fk = (lane >> 4) * 8;

  f32x4 acc[2][8] = {};

  for (int k0 = 0; k0 < 2048; k0 += 64) {
    __syncthreads();
#pragma unroll
    for (int c = 0; c < 4; ++c) {
      int lin = c * 256 + tid;
      int r = lin >> 3;
      int col = (lin & 7) << 3;
      GLD_LDS16(A + (size_t)(m0 + r) * 2048 + k0 + col, &lA[r][col]);
    }
#pragma unroll
    for (int c = 0; c < 4; ++c) {
      int lin = c * 256 + tid;
      int r = lin >> 3;
      int col = (lin & 7) << 3;
      GLD_LDS16(Bm + (size_t)(n0 + r) * 2048 + k0 + col, &lB[r][col]);
    }
    __syncthreads();
#pragma unroll
    for (int kk = 0; kk < 64; kk += 32) {
      bf16x8 av[2], bv[8];
#pragma unroll
      for (int i = 0; i < 2; ++i)
        av[i] = *(const bf16x8*)&lA[wm + i * 16 + frow][kk + fk];
#pragma unroll
      for (int i = 0; i < 8; ++i)
        bv[i] = *(const bf16x8*)&lB[i * 16 + frow][kk + fk];
#pragma unroll
      for (int mi = 0; mi < 2; ++mi)
#pragma unroll
        for (int ni = 0; ni < 8; ++ni)
          acc[mi][ni] = __builtin_amdgcn_mfma_f32_16x16x32_bf16(
              av[mi], bv[ni], acc[mi][ni], 0, 0, 0);
    }
  }

  const int r0 = (lane >> 4) * 4;
  const int cc = lane & 15;
  __hip_bfloat16* C = QKV + (size_t)z * (4096 * 2048);

  if (z < 2) {
    float invf[4];
#pragma unroll
    for (int ni = 0; ni < 4; ++ni)
      invf[ni] = __expf(-(float)(ni * 16 + cc) * 0.143911568312128f);
#pragma unroll
    for (int mi = 0; mi < 2; ++mi) {
#pragma unroll
      for (int rr = 0; rr < 4; ++rr) {
        int m = m0 + wm + mi * 16 + r0 + rr;
        float spos = (float)(m & 1023);
        __hip_bfloat16* crow = C + (size_t)m * 2048 + n0;
#pragma unroll
        for (int ni = 0; ni < 4; ++ni) {
          float sn, c;
          __sincosf(spos * invf[ni], &sn, &c);  // sin FIRST, then cos
          float x1 = acc[mi][ni][rr], x2 = acc[mi][ni + 4][rr];
          crow[ni * 16 + cc] = __float2bfloat16(x1 * c - x2 * sn);
          crow[(ni + 4) * 16 + cc] = __float2bfloat16(x2 * c + x1 * sn);
        }
      }
    }
  } else {
    // V: direct transposed write. n-tile spans exactly one head (d=128).
    const int hh = n0 >> 7;
#pragma unroll
    for (int mi = 0; mi < 2; ++mi) {
      int m = m0 + wm + mi * 16 + r0;  // +rr walks consecutive s
      int bb = m >> 10;
      int s = m & 1023;
      __hip_bfloat16* vdst = Vt + (((size_t)bb * 16 + hh) * 128) * 1024;
#pragma unroll
      for (int ni = 0; ni < 8; ++ni) {
        int d = ni * 16 + cc;
        __hip_bfloat16 hv[4] = {__float2bfloat16(acc[mi][ni][0]),
                                __float2bfloat16(acc[mi][ni][1]),
                                __float2bfloat16(acc[mi][ni][2]),
                                __float2bfloat16(acc[mi][ni][3])};
        unsigned long long u;
        __builtin_memcpy(&u, hv, 8);
        *(unsigned long long*)&vdst[(size_t)d * 1024 + s] = u;
      }
    }
  }
}

// ---------------------------------------------------------------- QK^T row-stat partials (k-chunked)
// Block = (z, m-tile, k-chunk of 256). Q rows in regs (wave owns 32 rows),
// K tiles streamed via global_load_lds; online (max, sumexp) over masked
// causal scores; 16-lane butterfly; write float2 partial per (chunk,row).
// Grid x = 20 = sum over my of nchunks(my), nchunks = (my>>1)+1.
__global__ __launch_bounds__(256) void qk_stats(
    const __hip_bfloat16* __restrict__ Qb, const __hip_bfloat16* __restrict__ Kb,
    const float* __restrict__ mask, float* __restrict__ pstat) {
  __shared__ alignas(16) __hip_bfloat16 lK[64][128];

  const int tid = threadIdx.x;
  const int z = blockIdx.y;
  int bx = blockIdx.x;
  int my = 0;
  for (; my < 8; ++my) {
    int n = (my >> 1) + 1;
    if (bx < n) break;
    bx -= n;
  }
  const int chunk = bx;
  const int m0 = my * 128;
  const int b = z >> 4, h = z & 15;
  const int kbeg = chunk * 256;
  const int kend = (kbeg + 256 < m0 + 128) ? (kbeg + 256) : (m0 + 128);

  const int lane = tid & 63;
  const int wid = tid >> 6;
  const int wm = wid * 32;
  const int frow = lane & 15;
  const int fk = (lane >> 4) * 8;
  const int r0 = (lane >> 4) * 4;
  const int cc = lane & 15;

  const __hip_bfloat16* Qh = Qb + ((size_t)b * 1024) * 2048 + h * 128;
  const __hip_bfloat16* Kh = Kb + ((size_t)b * 1024) * 2048 + h * 128;
  const float* mrow = mask + b * 1024;
  const float scale = 0.08838834764831845f;  // 1/sqrt(128)

  bf16x8 qf[2][4];
#pragma unroll
  for (int mi = 0; mi < 2; ++mi)
#pragma unroll
    for (int kq = 0; kq < 4; ++kq)
      qf[mi][kq] = *(const bf16x8*)
          &Qh[(size_t)(m0 + wm + mi * 16 + frow) * 2048 + kq * 32 + fk];

  float mx[2][4], sm[2][4];
#pragma unroll
  for (int mi = 0; mi < 2; ++mi)
#pragma unroll
    for (int rr = 0; rr < 4; ++rr) { mx[mi][rr] = -3.0e38f; sm[mi][rr] = 0.f; }

  for (int j0 = kbeg; j0 < kend; j0 += 64) {
    __syncthreads();
#pragma unroll
    for (int c = 0; c < 4; ++c) {
      int lin = c * 256 + tid;
      int r = lin >> 4;
      int col = (lin & 15) << 3;
      GLD_LDS16(Kh + (size_t)(j0 + r) * 2048 + col, &lK[r][col]);
    }
    __syncthreads();
    f32x4 as[2][4] = {};
#pragma unroll
    for (int kq = 0; kq < 4; ++kq) {
      bf16x8 bk[4];
#pragma unroll
      for (int ni = 0; ni < 4; ++ni)
        bk[ni] = *(const bf16x8*)&lK[ni * 16 + frow][kq * 32 + fk];
#pragma unroll
      for (int mi = 0; mi < 2; ++mi)
#pragma unroll
        for (int ni = 0; ni < 4; ++ni)
          as[mi][ni] = __builtin_amdgcn_mfma_f32_16x16x32_bf16(
              qf[mi][kq], bk[ni], as[mi][ni], 0, 0, 0);
    }
    float mk[4];
#pragma unroll
    for (int ni = 0; ni < 4; ++ni) mk[ni] = mrow[j0 + ni * 16 + cc];
#pragma unroll
    for (int mi = 0; mi < 2; ++mi) {
#pragma unroll
      for (int rr = 0; rr < 4; ++rr) {
        const int i = m0 + wm + mi * 16 + r0 + rr;
        float sv[4];
        bool ok[4];
#pragma unroll
        for (int ni = 0; ni < 4; ++ni) {
          int j = j0 + ni * 16 + cc;
          ok[ni] = (j <= i);
          sv[ni] = ok[ni] ? as[mi][ni][rr] * scale + mk[ni] : -3.0e38f;
        }
        float tm = fmaxf(fmaxf(sv[0], sv[1]), fmaxf(sv[2], sv[3]));
        if (tm > mx[mi][rr]) {
          sm[mi][rr] *= __expf(mx[mi][rr] - tm);
          mx[mi][rr] = tm;
        }
#pragma unroll
        for (int ni = 0; ni < 4; ++ni)
          sm[mi][rr] += ok[ni] ? __expf(sv[ni] - mx[mi][rr]) : 0.f;
      }
    }
  }

  // merge the 16 cc-lanes sharing each row; lane cc==0 writes the partial
  float2* p2 = (float2*)pstat + (((size_t)z * 8 + my) * 4 + chunk) * 128;
#pragma unroll
  for (int mi = 0; mi < 2; ++mi) {
#pragma unroll
    for (int rr = 0; rr < 4; ++rr) {
#pragma unroll
      for (int off = 1; off < 16; off <<= 1) {
        float om = __shfl_xor(mx[mi][rr], off, 64);
        float os = __shfl_xor(sm[mi][rr], off, 64);
        float nm = fmaxf(mx[mi][rr], om);
        sm[mi][rr] = sm[mi][rr] * __expf(mx[mi][rr] - nm) + os * __expf(om - nm);
        mx[mi][rr] = nm;
      }
      if (cc == 0)
        p2[wm + mi * 16 + r0 + rr] = float2{mx[mi][rr], sm[mi][rr]};
    }
  }
}

// ---------------------------------------------------------------- scores GEMM -> FINAL weights
// z=b*16+h, tiles with n0>m0 skipped. Prologue merges the <=4 chunk partials
// per row -> (mx, inv) in LDS. Epilogue: w = exp(s+mk-mx)*inv (0 above diag),
// written ONCE as the final fp32 attn_weights.
__global__ __launch_bounds__(256) void gemm_scores(
    const __hip_bfloat16* __restrict__ Qb, const __hip_bfloat16* __restrict__ Kb,
    const float* __restrict__ mask, float* __restrict__ Cbase,
    const float* __restrict__ pstat) {
  __shared__ alignas(16) __hip_bfloat16 lA[128][64];
  __shared__ alignas(16) __hip_bfloat16 lB[128][64];
  __shared__ float smx[128], sinv[128];

  const int tid = threadIdx.x;
  const int m0 = blockIdx.y * 128;
  const int n0 = blockIdx.x * 128;
  if (n0 > m0) return;  // tile fully above causal diagonal
  const int z = blockIdx.z;
  const int my = blockIdx.y;
  const int b = z >> 4, h = z & 15;
  const __hip_bfloat16* A = Qb + ((size_t)b * 1024) * 2048 + h * 128;
  const __hip_bfloat16* Bm = Kb + ((size_t)b * 1024) * 2048 + h * 128;

  // merge chunk partials -> global row stats
  if (tid < 128) {
    const float2* pp = (const float2*)pstat + ((size_t)z * 8 + my) * 4 * 128;
    int nc = (my >> 1) + 1;
    float m = -3.0e38f, s = 0.f;
    for (int c = 0; c < nc; ++c) {
      float2 p = pp[c * 128 + tid];
      float nm = fmaxf(m, p.x);
      s = s * __expf(m - nm) + p.y * __expf(p.x - nm);
      m = nm;
    }
    smx[tid] = m;
    sinv[tid] = 1.0f / s;
  }

  const int lane = tid & 63;
  const int wid = tid >> 6;
  const int wm = (wid & 1) * 64;
  const int wn = (wid >> 1) * 64;
  const int frow = lane & 15;
  const int fk = (lane >> 4) * 8;

  f32x4 acc[4][4] = {};

  for (int k0 = 0; k0 < 128; k0 += 64) {
    __syncthreads();
#pragma unroll
    for (int c = 0; c < 4; ++c) {
      int lin = c * 256 + tid;
      int r = lin >> 3;
      int col = (lin & 7) << 3;
      GLD_LDS16(A + (size_t)(m0 + r) * 2048 + k0 + col, &lA[r][col]);
    }
#pragma unroll
    for (int c = 0; c < 4; ++c) {
      int lin = c * 256 + tid;
      int r = lin >> 3;
      int col = (lin & 7) << 3;
      GLD_LDS16(Bm + (size_t)(n0 + r) * 2048 + k0 + col, &lB[r][col]);
    }
    __syncthreads();
#pragma unroll
    for (int kk = 0; kk < 64; kk += 32) {
      bf16x8 av[4], bv[4];
#pragma unroll
      for (int i = 0; i < 4; ++i)
        av[i] = *(const bf16x8*)&lA[wm + i * 16 + frow][kk + fk];
#pragma unroll
      for (int i = 0; i < 4; ++i)
        bv[i] = *(const bf16x8*)&lB[wn + i * 16 + frow][kk + fk];
#pragma unroll
      for (int mi = 0; mi < 4; ++mi)
#pragma unroll
        for (int ni = 0; ni < 4; ++ni)
          acc[mi][ni] = __builtin_amdgcn_mfma_f32_16x16x32_bf16(
              av[mi], bv[ni], acc[mi][ni], 0, 0, 0);
    }
  }

  const int r0 = (lane >> 4) * 4;
  const int cc = lane & 15;
  const float scale = 0.08838834764831845f;  // 1/sqrt(128)
  float* C = Cbase + (size_t)z * (1024 * 1024);
  const float* mrow = mask + b * 1024;
  float mk2[4];
#pragma unroll
  for (int ni = 0; ni < 4; ++ni) mk2[ni] = mrow[n0 + wn + ni * 16 + cc];

#pragma unroll
  for (int mi = 0; mi < 4; ++mi) {
#pragma unroll
    for (int r = 0; r < 4; ++r) {
      const int rl = wm + mi * 16 + r0 + r;
      const int i = m0 + rl;
      const float mxv = smx[rl];
      const float iv = sinv[rl];
      float* crow = &C[(size_t)i * 1024 + n0 + wn + cc];
#pragma unroll
      for (int ni = 0; ni < 4; ++ni) {
        int j = n0 + wn + ni * 16 + cc;
        float w = (j <= i)
                      ? __expf(acc[mi][ni][r] * scale + mk2[ni] - mxv) * iv
                      : 0.f;
        crow[ni * 16] = w;
      }
    }
  }
}

// ---------------------------------------------------------------- PV GEMM (plain)
// One block per (z, m-strip). A = final fp32 weights (reg convert -> bf16 ->
// LDS), B = Vt, K = m0+128 (weights zero past diagonal). attn-out bf16.
__global__ __launch_bounds__(256) void gemm_pv(
    const float* __restrict__ Sb, const __hip_bfloat16* __restrict__ Vt,
    __hip_bfloat16* __restrict__ AO) {
  __shared__ alignas(16) __hip_bfloat16 lA[128][64];
  __shared__ alignas(16) __hip_bfloat16 lB[128][64];

  const int tid = threadIdx.x;
  const int z = blockIdx.x;              // b*16+h
  const int ytile = 7 - blockIdx.y;      // big strips dispatch first
  const int m0 = ytile * 128;
  const int b = z >> 4, h = z & 15;
  const float* S = Sb + (size_t)z * (1024 * 1024);
  const __hip_bfloat16* Bm = Vt + (size_t)z * (128 * 1024);
  const int K = m0 + 128;

  // staging map: each row handled by 16 consecutive lanes
  const int sr = tid >> 4;
  const int scol = (tid & 15) << 2;

  const int lane = tid & 63;
  const int wid = tid >> 6;
  const int wm = (wid & 1) * 64;
  const int wn = (wid >> 1) * 64;
  const int frow = lane & 15;
  const int fk = (lane >> 4) * 8;

  f32x4 acc[4][4] = {};

  for (int k0 = 0; k0 < K; k0 += 64) {
    __syncthreads();
#pragma unroll
    for (int c = 0; c < 8; ++c) {
      int r = c * 16 + sr;
      float4 v = *(const float4*)&S[(size_t)(m0 + r) * 1024 + k0 + scol];
      __hip_bfloat16 hh[4] = {__float2bfloat16(v.x), __float2bfloat16(v.y),
                              __float2bfloat16(v.z), __float2bfloat16(v.w)};
      unsigned long long u;
      __builtin_memcpy(&u, hh, 8);
      *(unsigned long long*)&lA[r][scol] = u;
    }
#pragma unroll
    for (int c = 0; c < 4; ++c) {
      int lin = c * 256 + tid;
      int r = lin >> 3;
      int col = (lin & 7) << 3;
      GLD_LDS16(Bm + (size_t)r * 1024 + k0 + col, &lB[r][col]);
    }
    __syncthreads();
#pragma unroll
    for (int kk = 0; kk < 64; kk += 32) {
      bf16x8 av[4], bv[4];
#pragma unroll
      for (int i = 0; i < 4; ++i)
        av[i] = *(const bf16x8*)&lA[wm + i * 16 + frow][kk + fk];
#pragma unroll
      for (int i = 0; i < 4; ++i)
        bv[i] = *(const bf16x8*)&lB[wn + i * 16 + frow][kk + fk];
#pragma unroll
      for (int mi = 0; mi < 4; ++mi)
#pragma unroll
        for (int ni = 0; ni < 4; ++ni)
          acc[mi][ni] = __builtin_amdgcn_mfma_f32_16x16x32_bf16(
              av[mi], bv[ni], acc[mi][ni], 0, 0, 0);
    }
  }

  // epilogue: attn_out[b, i, h*128 + d], bf16
  const int r0 = (lane >> 4) * 4;
  const int cc = lane & 15;
  __hip_bfloat16* C = AO + ((size_t)b * 1024) * 2048 + h * 128;
#pragma unroll
  for (int mi = 0; mi < 4; ++mi)
#pragma unroll
    for (int ni = 0; ni < 4; ++ni)
#pragma unroll
      for (int r = 0; r < 4; ++r)
        C[(size_t)(m0 + wm + mi * 16 + r0 + r) * 2048 +
          (wn + ni * 16 + cc)] = __float2bfloat16(acc[mi][ni][r]);
}

// ---------------------------------------------------------------- output projection
__global__ __launch_bounds__(256) void gemm_out(
    const __hip_bfloat16* __restrict__ A, const __hip_bfloat16* __restrict__ Bm,
    float* __restrict__ Cbase) {
  __shared__ alignas(16) __hip_bfloat16 lA[128][64];
  __shared__ alignas(16) __hip_bfloat16 lB[128][64];

  const int tid = threadIdx.x;
  const int m0 = blockIdx.y * 128;
  const int n0 = blockIdx.x * 128;

  const int lane = tid & 63;
  const int wid = tid >> 6;
  const int wm = (wid & 1) * 64;
  const int wn = (wid >> 1) * 64;
  const int frow = lane & 15;
  const int fk = (lane >> 4) * 8;

  f32x4 acc[4][4] = {};

  for (int k0 = 0; k0 < 2048; k0 += 64) {
    __syncthreads();
#pragma unroll
    for (int c = 0; c < 4; ++c) {
      int lin = c * 256 + tid;
      int r = lin >> 3;
      int col = (lin & 7) << 3;
      GLD_LDS16(A + (size_t)(m0 + r) * 2048 + k0 + col, &lA[r][col]);
    }
#pragma unroll
    for (int c = 0; c < 4; ++c) {
      int lin = c * 256 + tid;
      int r = lin >> 3;
      int col = (lin & 7) << 3;
      GLD_LDS16(Bm + (size_t)(n0 + r) * 2048 + k0 + col, &lB[r][col]);
    }
    __syncthreads();
#pragma unroll
    for (int kk = 0; kk < 64; kk += 32) {
      bf16x8 av[4], bv[4];
#pragma unroll
      for (int i = 0; i < 4; ++i)
        av[i] = *(const bf16x8*)&lA[wm + i * 16 + frow][kk + fk];
#pragma unroll
      for (int i = 0; i < 4; ++i)
        bv[i] = *(const bf16x8*)&lB[wn + i * 16 + frow][kk + fk];
#pragma unroll
      for (int mi = 0; mi < 4; ++mi)
#pragma unroll
        for (int ni = 0; ni < 4; ++ni)
          acc[mi][ni] = __builtin_amdgcn_mfma_f32_16x16x32_bf16(
              av[mi], bv[ni], acc[mi][ni], 0, 0, 0);
    }
  }

  const int r0 = (lane >> 4) * 4;
  const int cc = lane & 15;
#pragma unroll
  for (int mi = 0; mi < 4; ++mi)
#pragma unroll
    for (int ni = 0; ni < 4; ++ni)
#pragma unroll
      for (int r = 0; r < 4; ++r)
        Cbase[(size_t)(m0 + wm + mi * 16 + r0 + r) * 2048 +
              (n0 + wn + ni * 16 + cc)] = acc[mi][ni][r];
}

// ---------------------------------------------------------------- launch
extern "C" void kernel_launch(void* const* d_in, const int* in_sizes, int n_in,
                              void* d_out, int out_size, void* d_ws,
                              size_t ws_size, hipStream_t stream) {
  const float* x = (const float*)d_in[0];
  const float* mask = (const float*)d_in[1];
  const float* Wq = (const float*)d_in[2];
  const float* Wk = (const float*)d_in[3];
  const float* Wv = (const float*)d_in[4];
  const float* Wo = (const float*)d_in[5];
  float* out = (float*)d_out;
  float* attnw = out + (size_t)4 * 1024 * 2048;  // fp32 weights region of d_out

  __hip_bfloat16* wsb = (__hip_bfloat16*)d_ws;
  __hip_bfloat16* Wob = wsb;                 //  4,194,304
  __hip_bfloat16* xb  = wsb + 4194304;       //  8,388,608
  __hip_bfloat16* Wqb = wsb + 12582912;      //  3x 4,194,304 (Wq,Wk,Wv contig)
  __hip_bfloat16* Qb  = wsb + 25165824;      //  3x 8,388,608 (Q,K slots used)
  __hip_bfloat16* Kb  = wsb + 33554432;
  __hip_bfloat16* Vt  = wsb + 50331648;      //  8,388,608
  __hip_bfloat16* AO  = wsb + 4194304;       //  8,388,608 (overlays dead xb)
  float* pstat = (float*)(wsb + 12582912);   //  2MB (overlays dead Wqkv)

  cast_all<<<12288, 256, 0, stream>>>(x, Wq, Wk, Wv, Wo, wsb);
  gemm_qkv<<<dim3(16, 32, 3), 256, 0, stream>>>(xb, Wqb, Qb, Vt);
  qk_stats<<<dim3(20, 64), 256, 0, stream>>>(Qb, Kb, mask, pstat);
  gemm_scores<<<dim3(8, 8, 64), 256, 0, stream>>>(Qb, Kb, mask, attnw, pstat);
  gemm_pv<<<dim3(64, 8), 256, 0, stream>>>(attnw, Vt, AO);
  gemm_out<<<dim3(16, 32), 256, 0, stream>>>(AO, Wob, out);
}

// Round 10
// 669.371 us; speedup vs baseline: 1.1648x; 1.0196x over previous
//
#include <hip/hip_runtime.h>
#include <hip/hip_bf16.h>

// MultiHeadAttention: B=4, S=1024, HIDDEN=2048, H=16, d=128, fp32 in/out.
// Pipeline (6 launches): fused cast->bf16, QKV gemm (+RoPE epilogue, V written
// directly transposed, L2-aware 4x4 panel-group block schedule), qk_stats,
// QK^T scores (merge stats, write FINAL fp32 attn_weights once),
// PV gemm (plain), output proj (L2-aware schedule).
//
// ws layout (bf16 elems), peak 117,440,512 bytes, lifetimes verified disjoint:
//   Wob   [0,          4194304)   live: cast .. gemm_out
//   xb    [4194304,   12582912)   live: cast .. gemm_qkv
//   Wqkv  [12582912,  25165824)   live: cast .. gemm_qkv
//   pstat [12582912,  13631488)   overlays dead Wqkv; live: stats .. scores (2MB)
//   QKV   [25165824,  50331648)   live: gemm_qkv .. pv (V slot unused)
//   Vt    [50331648,  58720256)   live: gemm_qkv .. pv
//   AO    [4194304,   12582912)   overlays dead xb; live: pv .. gemm_out

typedef __attribute__((ext_vector_type(8))) short bf16x8;
typedef __attribute__((ext_vector_type(4))) float f32x4;

#define GLD_LDS16(g, l)                                                      \
  __builtin_amdgcn_global_load_lds(                                          \
      (const __attribute__((address_space(1))) unsigned int*)(g),            \
      (__attribute__((address_space(3))) unsigned int*)(l), 16, 0, 0)

// ---------------------------------------------------------------- fused cast fp32->bf16
__global__ __launch_bounds__(256) void cast_all(
    const float* __restrict__ x, const float* __restrict__ Wq,
    const float* __restrict__ Wk, const float* __restrict__ Wv,
    const float* __restrict__ Wo, __hip_bfloat16* __restrict__ ws) {
  int idx = blockIdx.x * 256 + threadIdx.x;
  const float* src;
  __hip_bfloat16* dst;
  int off;
  if (idx < 1048576) {
    src = x; dst = ws + 4194304; off = idx;             // xb
  } else if (idx < 1572864) {
    src = Wq; dst = ws + 12582912; off = idx - 1048576; // Wqb
  } else if (idx < 2097152) {
    src = Wk; dst = ws + 16777216; off = idx - 1572864; // Wkb
  } else if (idx < 2621440) {
    src = Wv; dst = ws + 20971520; off = idx - 2097152; // Wvb
  } else {
    src = Wo; dst = ws; off = idx - 2621440;            // Wob
  }
  const float4* p = (const float4*)src;
  float4 a = p[(size_t)off * 2], b = p[(size_t)off * 2 + 1];
  __hip_bfloat16 h[8] = {__float2bfloat16(a.x), __float2bfloat16(a.y),
                         __float2bfloat16(a.z), __float2bfloat16(a.w),
                         __float2bfloat16(b.x), __float2bfloat16(b.y),
                         __float2bfloat16(b.z), __float2bfloat16(b.w)};
  uint4 u;
  __builtin_memcpy(&u, h, 16);
  ((uint4*)dst)[off] = u;
}

// ---------------------------------------------------------------- QKV GEMM + fused RoPE + V-transpose
// Flat grid 1536. Block schedule: T1 XCD-chunk inverse (1536%8==0, bijective)
// -> virtual id; vid decodes to 4x4 (x,y) panel groups (4 A + 4 B panels =
// 4MB = one XCD L2), x-major so consecutive groups reuse the same A panels.
__global__ __launch_bounds__(256) void gemm_qkv(
    const __hip_bfloat16* __restrict__ A, const __hip_bfloat16* __restrict__ W,
    __hip_bfloat16* __restrict__ QKV, __hip_bfloat16* __restrict__ Vt) {
  __shared__ alignas(16) __hip_bfloat16 lA[128][64];
  __shared__ alignas(16) __hip_bfloat16 lB[128][64];

  const int tid = threadIdx.x;
  // ---- L2-aware schedule decode
  const int bid = blockIdx.x;                 // 0..1535
  const int vid = (bid & 7) * 192 + (bid >> 3);  // XCD-chunked, bijective
  const int gid = vid >> 4, lid = vid & 15;      // 96 groups of 16
  const int z = gid / 32;                        // 32 groups per z
  const int gr = gid % 32;
  const int gx = gr & 3, gy = gr >> 2;           // x-major group order
  const int xt = gx * 4 + (lid & 3);             // 0..15
  const int yt = gy * 4 + (lid >> 2);            // 0..31
  const int m0 = yt * 128;
  const int n0 = xt * 128;
  const __hip_bfloat16* Bm = W + (size_t)z * (2048 * 2048);

  const int lane = tid & 63;
  const int wid = tid >> 6;
  const int wm = wid * 32;
  const int frow = lane & 15;
  const int fk = (lane >> 4) * 8;

  f32x4 acc[2][8] = {};

  for (int k0 = 0; k0 < 2048; k0 += 64) {
    __syncthreads();
#pragma unroll
    for (int c = 0; c < 4; ++c) {
      int lin = c * 256 + tid;
      int r = lin >> 3;
      int col = (lin & 7) << 3;
      GLD_LDS16(A + (size_t)(m0 + r) * 2048 + k0 + col, &lA[r][col]);
    }
#pragma unroll
    for (int c = 0; c < 4; ++c) {
      int lin = c * 256 + tid;
      int r = lin >> 3;
      int col = (lin & 7) << 3;
      GLD_LDS16(Bm + (size_t)(n0 + r) * 2048 + k0 + col, &lB[r][col]);
    }
    __syncthreads();
#pragma unroll
    for (int kk = 0; kk < 64; kk += 32) {
      bf16x8 av[2], bv[8];
#pragma unroll
      for (int i = 0; i < 2; ++i)
        av[i] = *(const bf16x8*)&lA[wm + i * 16 + frow][kk + fk];
#pragma unroll
      for (int i = 0; i < 8; ++i)
        bv[i] = *(const bf16x8*)&lB[i * 16 + frow][kk + fk];
#pragma unroll
      for (int mi = 0; mi < 2; ++mi)
#pragma unroll
        for (int ni = 0; ni < 8; ++ni)
          acc[mi][ni] = __builtin_amdgcn_mfma_f32_16x16x32_bf16(
              av[mi], bv[ni], acc[mi][ni], 0, 0, 0);
    }
  }

  const int r0 = (lane >> 4) * 4;
  const int cc = lane & 15;
  __hip_bfloat16* C = QKV + (size_t)z * (4096 * 2048);

  if (z < 2) {
    float invf[4];
#pragma unroll
    for (int ni = 0; ni < 4; ++ni)
      invf[ni] = __expf(-(float)(ni * 16 + cc) * 0.143911568312128f);
#pragma unroll
    for (int mi = 0; mi < 2; ++mi) {
#pragma unroll
      for (int rr = 0; rr < 4; ++rr) {
        int m = m0 + wm + mi * 16 + r0 + rr;
        float spos = (float)(m & 1023);
        __hip_bfloat16* crow = C + (size_t)m * 2048 + n0;
#pragma unroll
        for (int ni = 0; ni < 4; ++ni) {
          float sn, c;
          __sincosf(spos * invf[ni], &sn, &c);  // sin FIRST, then cos
          float x1 = acc[mi][ni][rr], x2 = acc[mi][ni + 4][rr];
          crow[ni * 16 + cc] = __float2bfloat16(x1 * c - x2 * sn);
          crow[(ni + 4) * 16 + cc] = __float2bfloat16(x2 * c + x1 * sn);
        }
      }
    }
  } else {
    // V: direct transposed write. n-tile spans exactly one head (d=128).
    const int hh = n0 >> 7;
#pragma unroll
    for (int mi = 0; mi < 2; ++mi) {
      int m = m0 + wm + mi * 16 + r0;  // +rr walks consecutive s
      int bb = m >> 10;
      int s = m & 1023;
      __hip_bfloat16* vdst = Vt + (((size_t)bb * 16 + hh) * 128) * 1024;
#pragma unroll
      for (int ni = 0; ni < 8; ++ni) {
        int d = ni * 16 + cc;
        __hip_bfloat16 hv[4] = {__float2bfloat16(acc[mi][ni][0]),
                                __float2bfloat16(acc[mi][ni][1]),
                                __float2bfloat16(acc[mi][ni][2]),
                                __float2bfloat16(acc[mi][ni][3])};
        unsigned long long u;
        __builtin_memcpy(&u, hv, 8);
        *(unsigned long long*)&vdst[(size_t)d * 1024 + s] = u;
      }
    }
  }
}

// ---------------------------------------------------------------- QK^T row-stat partials (k-chunked)
__global__ __launch_bounds__(256) void qk_stats(
    const __hip_bfloat16* __restrict__ Qb, const __hip_bfloat16* __restrict__ Kb,
    const float* __restrict__ mask, float* __restrict__ pstat) {
  __shared__ alignas(16) __hip_bfloat16 lK[64][128];

  const int tid = threadIdx.x;
  const int z = blockIdx.y;
  int bx = blockIdx.x;
  int my = 0;
  for (; my < 8; ++my) {
    int n = (my >> 1) + 1;
    if (bx < n) break;
    bx -= n;
  }
  const int chunk = bx;
  const int m0 = my * 128;
  const int b = z >> 4, h = z & 15;
  const int kbeg = chunk * 256;
  const int kend = (kbeg + 256 < m0 + 128) ? (kbeg + 256) : (m0 + 128);

  const int lane = tid & 63;
  const int wid = tid >> 6;
  const int wm = wid * 32;
  const int frow = lane & 15;
  const int fk = (lane >> 4) * 8;
  const int r0 = (lane >> 4) * 4;
  const int cc = lane & 15;

  const __hip_bfloat16* Qh = Qb + ((size_t)b * 1024) * 2048 + h * 128;
  const __hip_bfloat16* Kh = Kb + ((size_t)b * 1024) * 2048 + h * 128;
  const float* mrow = mask + b * 1024;
  const float scale = 0.08838834764831845f;  // 1/sqrt(128)

  bf16x8 qf[2][4];
#pragma unroll
  for (int mi = 0; mi < 2; ++mi)
#pragma unroll
    for (int kq = 0; kq < 4; ++kq)
      qf[mi][kq] = *(const bf16x8*)
          &Qh[(size_t)(m0 + wm + mi * 16 + frow) * 2048 + kq * 32 + fk];

  float mx[2][4], sm[2][4];
#pragma unroll
  for (int mi = 0; mi < 2; ++mi)
#pragma unroll
    for (int rr = 0; rr < 4; ++rr) { mx[mi][rr] = -3.0e38f; sm[mi][rr] = 0.f; }

  for (int j0 = kbeg; j0 < kend; j0 += 64) {
    __syncthreads();
#pragma unroll
    for (int c = 0; c < 4; ++c) {
      int lin = c * 256 + tid;
      int r = lin >> 4;
      int col = (lin & 15) << 3;
      GLD_LDS16(Kh + (size_t)(j0 + r) * 2048 + col, &lK[r][col]);
    }
    __syncthreads();
    f32x4 as[2][4] = {};
#pragma unroll
    for (int kq = 0; kq < 4; ++kq) {
      bf16x8 bk[4];
#pragma unroll
      for (int ni = 0; ni < 4; ++ni)
        bk[ni] = *(const bf16x8*)&lK[ni * 16 + frow][kq * 32 + fk];
#pragma unroll
      for (int mi = 0; mi < 2; ++mi)
#pragma unroll
        for (int ni = 0; ni < 4; ++ni)
          as[mi][ni] = __builtin_amdgcn_mfma_f32_16x16x32_bf16(
              qf[mi][kq], bk[ni], as[mi][ni], 0, 0, 0);
    }
    float mk[4];
#pragma unroll
    for (int ni = 0; ni < 4; ++ni) mk[ni] = mrow[j0 + ni * 16 + cc];
#pragma unroll
    for (int mi = 0; mi < 2; ++mi) {
#pragma unroll
      for (int rr = 0; rr < 4; ++rr) {
        const int i = m0 + wm + mi * 16 + r0 + rr;
        float sv[4];
        bool ok[4];
#pragma unroll
        for (int ni = 0; ni < 4; ++ni) {
          int j = j0 + ni * 16 + cc;
          ok[ni] = (j <= i);
          sv[ni] = ok[ni] ? as[mi][ni][rr] * scale + mk[ni] : -3.0e38f;
        }
        float tm = fmaxf(fmaxf(sv[0], sv[1]), fmaxf(sv[2], sv[3]));
        if (tm > mx[mi][rr]) {
          sm[mi][rr] *= __expf(mx[mi][rr] - tm);
          mx[mi][rr] = tm;
        }
#pragma unroll
        for (int ni = 0; ni < 4; ++ni)
          sm[mi][rr] += ok[ni] ? __expf(sv[ni] - mx[mi][rr]) : 0.f;
      }
    }
  }

  // merge the 16 cc-lanes sharing each row; lane cc==0 writes the partial
  float2* p2 = (float2*)pstat + (((size_t)z * 8 + my) * 4 + chunk) * 128;
#pragma unroll
  for (int mi = 0; mi < 2; ++mi) {
#pragma unroll
    for (int rr = 0; rr < 4; ++rr) {
#pragma unroll
      for (int off = 1; off < 16; off <<= 1) {
        float om = __shfl_xor(mx[mi][rr], off, 64);
        float os = __shfl_xor(sm[mi][rr], off, 64);
        float nm = fmaxf(mx[mi][rr], om);
        sm[mi][rr] = sm[mi][rr] * __expf(mx[mi][rr] - nm) + os * __expf(om - nm);
        mx[mi][rr] = nm;
      }
      if (cc == 0)
        p2[wm + mi * 16 + r0 + rr] = float2{mx[mi][rr], sm[mi][rr]};
    }
  }
}

// ---------------------------------------------------------------- scores GEMM -> FINAL weights
__global__ __launch_bounds__(256) void gemm_scores(
    const __hip_bfloat16* __restrict__ Qb, const __hip_bfloat16* __restrict__ Kb,
    const float* __restrict__ mask, float* __restrict__ Cbase,
    const float* __restrict__ pstat) {
  __shared__ alignas(16) __hip_bfloat16 lA[128][64];
  __shared__ alignas(16) __hip_bfloat16 lB[128][64];
  __shared__ float smx[128], sinv[128];

  const int tid = threadIdx.x;
  const int m0 = blockIdx.y * 128;
  const int n0 = blockIdx.x * 128;
  if (n0 > m0) return;  // tile fully above causal diagonal
  const int z = blockIdx.z;
  const int my = blockIdx.y;
  const int b = z >> 4, h = z & 15;
  const __hip_bfloat16* A = Qb + ((size_t)b * 1024) * 2048 + h * 128;
  const __hip_bfloat16* Bm = Kb + ((size_t)b * 1024) * 2048 + h * 128;

  // merge chunk partials -> global row stats
  if (tid < 128) {
    const float2* pp = (const float2*)pstat + ((size_t)z * 8 + my) * 4 * 128;
    int nc = (my >> 1) + 1;
    float m = -3.0e38f, s = 0.f;
    for (int c = 0; c < nc; ++c) {
      float2 p = pp[c * 128 + tid];
      float nm = fmaxf(m, p.x);
      s = s * __expf(m - nm) + p.y * __expf(p.x - nm);
      m = nm;
    }
    smx[tid] = m;
    sinv[tid] = 1.0f / s;
  }

  const int lane = tid & 63;
  const int wid = tid >> 6;
  const int wm = (wid & 1) * 64;
  const int wn = (wid >> 1) * 64;
  const int frow = lane & 15;
  const int fk = (lane >> 4) * 8;

  f32x4 acc[4][4] = {};

  for (int k0 = 0; k0 < 128; k0 += 64) {
    __syncthreads();
#pragma unroll
    for (int c = 0; c < 4; ++c) {
      int lin = c * 256 + tid;
      int r = lin >> 3;
      int col = (lin & 7) << 3;
      GLD_LDS16(A + (size_t)(m0 + r) * 2048 + k0 + col, &lA[r][col]);
    }
#pragma unroll
    for (int c = 0; c < 4; ++c) {
      int lin = c * 256 + tid;
      int r = lin >> 3;
      int col = (lin & 7) << 3;
      GLD_LDS16(Bm + (size_t)(n0 + r) * 2048 + k0 + col, &lB[r][col]);
    }
    __syncthreads();
#pragma unroll
    for (int kk = 0; kk < 64; kk += 32) {
      bf16x8 av[4], bv[4];
#pragma unroll
      for (int i = 0; i < 4; ++i)
        av[i] = *(const bf16x8*)&lA[wm + i * 16 + frow][kk + fk];
#pragma unroll
      for (int i = 0; i < 4; ++i)
        bv[i] = *(const bf16x8*)&lB[wn + i * 16 + frow][kk + fk];
#pragma unroll
      for (int mi = 0; mi < 4; ++mi)
#pragma unroll
        for (int ni = 0; ni < 4; ++ni)
          acc[mi][ni] = __builtin_amdgcn_mfma_f32_16x16x32_bf16(
              av[mi], bv[ni], acc[mi][ni], 0, 0, 0);
    }
  }

  const int r0 = (lane >> 4) * 4;
  const int cc = lane & 15;
  const float scale = 0.08838834764831845f;  // 1/sqrt(128)
  float* C = Cbase + (size_t)z * (1024 * 1024);
  const float* mrow = mask + b * 1024;
  float mk2[4];
#pragma unroll
  for (int ni = 0; ni < 4; ++ni) mk2[ni] = mrow[n0 + wn + ni * 16 + cc];

#pragma unroll
  for (int mi = 0; mi < 4; ++mi) {
#pragma unroll
    for (int r = 0; r < 4; ++r) {
      const int rl = wm + mi * 16 + r0 + r;
      const int i = m0 + rl;
      const float mxv = smx[rl];
      const float iv = sinv[rl];
      float* crow = &C[(size_t)i * 1024 + n0 + wn + cc];
#pragma unroll
      for (int ni = 0; ni < 4; ++ni) {
        int j = n0 + wn + ni * 16 + cc;
        float w = (j <= i)
                      ? __expf(acc[mi][ni][r] * scale + mk2[ni] - mxv) * iv
                      : 0.f;
        crow[ni * 16] = w;
      }
    }
  }
}

// ---------------------------------------------------------------- PV GEMM (plain)
__global__ __launch_bounds__(256) void gemm_pv(
    const float* __restrict__ Sb, const __hip_bfloat16* __restrict__ Vt,
    __hip_bfloat16* __restrict__ AO) {
  __shared__ alignas(16) __hip_bfloat16 lA[128][64];
  __shared__ alignas(16) __hip_bfloat16 lB[128][64];

  const int tid = threadIdx.x;
  const int z = blockIdx.x;              // b*16+h
  const int ytile = 7 - blockIdx.y;      // big strips dispatch first
  const int m0 = ytile * 128;
  const int b = z >> 4, h = z & 15;
  const float* S = Sb + (size_t)z * (1024 * 1024);
  const __hip_bfloat16* Bm = Vt + (size_t)z * (128 * 1024);
  const int K = m0 + 128;

  // staging map: each row handled by 16 consecutive lanes
  const int sr = tid >> 4;
  const int scol = (tid & 15) << 2;

  const int lane = tid & 63;
  const int wid = tid >> 6;
  const int wm = (wid & 1) * 64;
  const int wn = (wid >> 1) * 64;
  const int frow = lane & 15;
  const int fk = (lane >> 4) * 8;

  f32x4 acc[4][4] = {};

  for (int k0 = 0; k0 < K; k0 += 64) {
    __syncthreads();
#pragma unroll
    for (int c = 0; c < 8; ++c) {
      int r = c * 16 + sr;
      float4 v = *(const float4*)&S[(size_t)(m0 + r) * 1024 + k0 + scol];
      __hip_bfloat16 hh[4] = {__float2bfloat16(v.x), __float2bfloat16(v.y),
                              __float2bfloat16(v.z), __float2bfloat16(v.w)};
      unsigned long long u;
      __builtin_memcpy(&u, hh, 8);
      *(unsigned long long*)&lA[r][scol] = u;
    }
#pragma unroll
    for (int c = 0; c < 4; ++c) {
      int lin = c * 256 + tid;
      int r = lin >> 3;
      int col = (lin & 7) << 3;
      GLD_LDS16(Bm + (size_t)r * 1024 + k0 + col, &lB[r][col]);
    }
    __syncthreads();
#pragma unroll
    for (int kk = 0; kk < 64; kk += 32) {
      bf16x8 av[4], bv[4];
#pragma unroll
      for (int i = 0; i < 4; ++i)
        av[i] = *(const bf16x8*)&lA[wm + i * 16 + frow][kk + fk];
#pragma unroll
      for (int i = 0; i < 4; ++i)
        bv[i] = *(const bf16x8*)&lB[wn + i * 16 + frow][kk + fk];
#pragma unroll
      for (int mi = 0; mi < 4; ++mi)
#pragma unroll
        for (int ni = 0; ni < 4; ++ni)
          acc[mi][ni] = __builtin_amdgcn_mfma_f32_16x16x32_bf16(
              av[mi], bv[ni], acc[mi][ni], 0, 0, 0);
    }
  }

  // epilogue: attn_out[b, i, h*128 + d], bf16
  const int r0 = (lane >> 4) * 4;
  const int cc = lane & 15;
  __hip_bfloat16* C = AO + ((size_t)b * 1024) * 2048 + h * 128;
#pragma unroll
  for (int mi = 0; mi < 4; ++mi)
#pragma unroll
    for (int ni = 0; ni < 4; ++ni)
#pragma unroll
      for (int r = 0; r < 4; ++r)
        C[(size_t)(m0 + wm + mi * 16 + r0 + r) * 2048 +
          (wn + ni * 16 + cc)] = __float2bfloat16(acc[mi][ni][r]);
}

// ---------------------------------------------------------------- output projection
// Flat grid 512, same L2-aware 4x4 panel-group schedule (cpx = 64).
__global__ __launch_bounds__(256) void gemm_out(
    const __hip_bfloat16* __restrict__ A, const __hip_bfloat16* __restrict__ Bm,
    float* __restrict__ Cbase) {
  __shared__ alignas(16) __hip_bfloat16 lA[128][64];
  __shared__ alignas(16) __hip_bfloat16 lB[128][64];

  const int tid = threadIdx.x;
  const int bid = blockIdx.x;                    // 0..511
  const int vid = (bid & 7) * 64 + (bid >> 3);   // XCD-chunked, bijective
  const int gid = vid >> 4, lid = vid & 15;      // 32 groups of 16
  const int gx = gid & 3, gy = gid >> 2;         // x-major group order
  const int m0 = (gy * 4 + (lid >> 2)) * 128;    // yt 0..31
  const int n0 = (gx * 4 + (lid & 3)) * 128;     // xt 0..15

  const int lane = tid & 63;
  const int wid = tid >> 6;
  const int wm = (wid & 1) * 64;
  const int wn = (wid >> 1) * 64;
  const int frow = lane & 15;
  const int fk = (lane >> 4) * 8;

  f32x4 acc[4][4] = {};

  for (int k0 = 0; k0 < 2048; k0 += 64) {
    __syncthreads();
#pragma unroll
    for (int c = 0; c < 4; ++c) {
      int lin = c * 256 + tid;
      int r = lin >> 3;
      int col = (lin & 7) << 3;
      GLD_LDS16(A + (size_t)(m0 + r) * 2048 + k0 + col, &lA[r][col]);
    }
#pragma unroll
    for (int c = 0; c < 4; ++c) {
      int lin = c * 256 + tid;
      int r = lin >> 3;
      int col = (lin & 7) << 3;
      GLD_LDS16(Bm + (size_t)(n0 + r) * 2048 + k0 + col, &lB[r][col]);
    }
    __syncthreads();
#pragma unroll
    for (int kk = 0; kk < 64; kk += 32) {
      bf16x8 av[4], bv[4];
#pragma unroll
      for (int i = 0; i < 4; ++i)
        av[i] = *(const bf16x8*)&lA[wm + i * 16 + frow][kk + fk];
#pragma unroll
      for (int i = 0; i < 4; ++i)
        bv[i] = *(const bf16x8*)&lB[wn + i * 16 + frow][kk + fk];
#pragma unroll
      for (int mi = 0; mi < 4; ++mi)
#pragma unroll
        for (int ni = 0; ni < 4; ++ni)
          acc[mi][ni] = __builtin_amdgcn_mfma_f32_16x16x32_bf16(
              av[mi], bv[ni], acc[mi][ni], 0, 0, 0);
    }
  }

  const int r0 = (lane >> 4) * 4;
  const int cc = lane & 15;
#pragma unroll
  for (int mi = 0; mi < 4; ++mi)
#pragma unroll
    for (int ni = 0; ni < 4; ++ni)
#pragma unroll
      for (int r = 0; r < 4; ++r)
        Cbase[(size_t)(m0 + wm + mi * 16 + r0 + r) * 2048 +
              (n0 + wn + ni * 16 + cc)] = acc[mi][ni][r];
}

// ---------------------------------------------------------------- launch
extern "C" void kernel_launch(void* const* d_in, const int* in_sizes, int n_in,
                              void* d_out, int out_size, void* d_ws,
                              size_t ws_size, hipStream_t stream) {
  const float* x = (const float*)d_in[0];
  const float* mask = (const float*)d_in[1];
  const float* Wq = (const float*)d_in[2];
  const float* Wk = (const float*)d_in[3];
  const float* Wv = (const float*)d_in[4];
  const float* Wo = (const float*)d_in[5];
  float* out = (float*)d_out;
  float* attnw = out + (size_t)4 * 1024 * 2048;  // fp32 weights region of d_out

  __hip_bfloat16* wsb = (__hip_bfloat16*)d_ws;
  __hip_bfloat16* Wob = wsb;                 //  4,194,304
  __hip_bfloat16* xb  = wsb + 4194304;       //  8,388,608
  __hip_bfloat16* Wqb = wsb + 12582912;      //  3x 4,194,304 (Wq,Wk,Wv contig)
  __hip_bfloat16* Qb  = wsb + 25165824;      //  3x 8,388,608 (Q,K slots used)
  __hip_bfloat16* Kb  = wsb + 33554432;
  __hip_bfloat16* Vt  = wsb + 50331648;      //  8,388,608
  __hip_bfloat16* AO  = wsb + 4194304;       //  8,388,608 (overlays dead xb)
  float* pstat = (float*)(wsb + 12582912);   //  2MB (overlays dead Wqkv)

  cast_all<<<12288, 256, 0, stream>>>(x, Wq, Wk, Wv, Wo, wsb);
  gemm_qkv<<<1536, 256, 0, stream>>>(xb, Wqb, Qb, Vt);
  qk_stats<<<dim3(20, 64), 256, 0, stream>>>(Qb, Kb, mask, pstat);
  gemm_scores<<<dim3(8, 8, 64), 256, 0, stream>>>(Qb, Kb, mask, attnw, pstat);
  gemm_pv<<<dim3(64, 8), 256, 0, stream>>>(attnw, Vt, AO);
  gemm_out<<<512, 256, 0, stream>>>(AO, Wob, out);
}